// Round 2
// baseline (1844.886 us; speedup 1.0000x reference)
//
#include <hip/hip_runtime.h>
#include <hip/hip_bf16.h>
#include <math.h>

#define N_NODES 100000
#define N_EDGES 1600000
#define F_IN 512
#define F_GNN 128
#define HID 64
#define Z_DIM 64
#define N_GRAPHS 512
#define N_REGIONS 196      // 512 nodes per region
#define QTR 128            // nodes per accumulator block (quarter region)

typedef __attribute__((ext_vector_type(8))) short short8;
typedef __attribute__((ext_vector_type(4))) float f32x4;

// ---------- small device helpers ----------
__device__ __forceinline__ float eluf(float v) { return v > 0.f ? v : expm1f(v); }
__device__ __forceinline__ float softplusf(float v) {
  return fmaxf(v, 0.f) + log1pf(expf(-fabsf(v)));
}
__device__ __forceinline__ float sigmoidf(float v) { return 1.f / (1.f + expf(-v)); }

__device__ __forceinline__ unsigned short f2bf(float f) {
  unsigned int u = __float_as_uint(f);
  u = (u + 0x7fffu + ((u >> 16) & 1u)) >> 16;
  return (unsigned short)u;
}
// packed f32x2 -> bf16x2 (low = a, high = b)
__device__ __forceinline__ unsigned int f2bf2(float a, float b) {
  __hip_bfloat162 h = __float22bfloat162_rn(make_float2(a, b));
  unsigned int u;
  __builtin_memcpy(&u, &h, 4);
  return u;
}
__device__ __forceinline__ float bf_lo(unsigned int u) { return __uint_as_float(u << 16); }
__device__ __forceinline__ float bf_hi(unsigned int u) { return __uint_as_float(u & 0xffff0000u); }

// ---------- init: WgT transpose, zero hist/gx/gcnt ----------
__global__ __launch_bounds__(256) void k_init(
    const float* __restrict__ Wg, unsigned short* __restrict__ WgT,
    int* __restrict__ hist, float* __restrict__ gx, float* __restrict__ gcnt) {
  int i = blockIdx.x * 256 + threadIdx.x;   // 131072 threads
  if (i < 65536) {
    int n = i >> 9, k = i & 511;
    WgT[i] = f2bf(Wg[k * F_GNN + n]);
  }
  if (i < 100352) hist[i] = 0;
  gx[i] = 0.f;
  if (i < 512) gcnt[i] = 0.f;
}

// ---------- per-node in-degree histogram (global atomics) ----------
__global__ __launch_bounds__(256) void k_hist(const int* __restrict__ ei,
                                              int* __restrict__ hist) {
  int b = blockIdx.x, t = threadIdx.x;
#pragma unroll
  for (int j = 0; j < 4; j++) {
    int e = b * 1024 + t + 256 * j;
    if (e < N_EDGES) atomicAdd(&hist[ei[N_EDGES + e]], 1);
  }
}

// ---------- per-region: dinv from hist + region edge count ----------
__global__ __launch_bounds__(256) void k_rsum(const int* __restrict__ hist,
                                              float* __restrict__ dinv,
                                              int* __restrict__ rcnt) {
  __shared__ int s[256];
  int r = blockIdx.x, t = threadIdx.x;
  int n0 = (r << 9) + 2 * t;
  int a0 = hist[n0], a1 = hist[n0 + 1];   // hist sized 100352 = 196*512 exactly
  if (n0 < N_NODES)     dinv[n0]     = rsqrtf(1.f + (float)a0);
  if (n0 + 1 < N_NODES) dinv[n0 + 1] = rsqrtf(1.f + (float)a1);
  s[t] = a0 + a1;
  __syncthreads();
#pragma unroll
  for (int d = 128; d > 0; d >>= 1) {
    if (t < d) s[t] += s[t + d];
    __syncthreads();
  }
  if (t == 0) rcnt[r] = s[0];
}

// ---------- scan 196 region counts -> rbase (excl) + seed cursors ----------
__global__ __launch_bounds__(256) void k_rscan(int* __restrict__ rcnt,  // == cursor_r
                                               int* __restrict__ rbase) {
  __shared__ int s[256];
  int t = threadIdx.x;
  s[t] = (t < N_REGIONS) ? rcnt[t] : 0;
  __syncthreads();
#pragma unroll
  for (int d = 1; d < 256; d <<= 1) {
    int v = (t >= d) ? s[t - d] : 0;
    __syncthreads();
    s[t] += v;
    __syncthreads();
  }
  int excl = (t > 0) ? s[t - 1] : 0;
  rbase[t] = excl;
  rcnt[t] = excl;               // cursor seed
  if (t == 255) rbase[N_REGIONS] = s[255];   // = N_EDGES
}

// ---------- bucket edges into 196 regions, packed (src | dstl<<17) ----------
__global__ __launch_bounds__(256) void k_bucket(
    const int* __restrict__ ei, int* __restrict__ cursor_r,
    unsigned int* __restrict__ pairs) {
  __shared__ int lhist[256];
  __shared__ int lofs[256];
  __shared__ int lcur[256];
  __shared__ int gbase[256];
  __shared__ int sc[256];
  __shared__ unsigned int lpairs[4096];   // 16 KB

  const int b = blockIdx.x, t = threadIdx.x;
  const int e0 = b * 4096;
  const int n_b = min(4096, N_EDGES - e0);

  lhist[t] = 0;
  lcur[t] = 0;
  __syncthreads();

  int srcv[16], dstv[16];
#pragma unroll
  for (int j = 0; j < 16; j++) {
    int e = e0 + t + 256 * j;
    if (e < N_EDGES) {
      srcv[j] = ei[e];
      dstv[j] = ei[N_EDGES + e];
      atomicAdd(&lhist[dstv[j] >> 9], 1);
    } else {
      dstv[j] = -1;
    }
  }
  __syncthreads();

  // exclusive scan of lhist -> lofs
  sc[t] = lhist[t];
  __syncthreads();
#pragma unroll
  for (int d = 1; d < 256; d <<= 1) {
    int v = (t >= d) ? sc[t - d] : 0;
    __syncthreads();
    sc[t] += v;
    __syncthreads();
  }
  lofs[t] = (t > 0) ? sc[t - 1] : 0;
  if (t < N_REGIONS && lhist[t] > 0) gbase[t] = atomicAdd(&cursor_r[t], lhist[t]);
  __syncthreads();

  // local scatter into LDS, region-contiguous, packed
#pragma unroll
  for (int j = 0; j < 16; j++) {
    if (dstv[j] >= 0) {
      int r = dstv[j] >> 9;
      int pos = lofs[r] + atomicAdd(&lcur[r], 1);
      lpairs[pos] = (unsigned)srcv[j] | ((unsigned)(dstv[j] & 511) << 17);
    }
  }
  __syncthreads();

  // flush: consecutive i -> consecutive slot within region run (coalesced)
  for (int i = t; i < n_b; i += 256) {
    int lo = 0, hi = N_REGIONS;
    while (hi - lo > 1) {
      int mid = (lo + hi) >> 1;
      if (lofs[mid] <= i) lo = mid; else hi = mid;
    }
    pairs[gbase[lo] + (i - lofs[lo])] = lpairs[i];
  }
}

// ---------- MFMA GEMM: sxw_bf16 = bf16((x @ Wg) * dinv[row]) ----------
__global__ __launch_bounds__(256) void k_gemm(
    const float* __restrict__ x, const unsigned short* __restrict__ WgT,
    const float* __restrict__ dinv, unsigned short* __restrict__ sxw) {
  __shared__ unsigned short As[128][32];   // [m][k] bf16
  __shared__ unsigned short Bs[128][32];   // [n][k] bf16 (B^T)

  const int t = threadIdx.x;
  const int lane15 = t & 15;
  const int quad = (t & 63) >> 4;
  const int wave = t >> 6;
  const int wm = (wave & 1) * 64;
  const int wn = (wave >> 1) * 64;
  const int row0 = blockIdx.x * 128;

  f32x4 acc[4][4];
#pragma unroll
  for (int mi = 0; mi < 4; mi++)
#pragma unroll
    for (int ni = 0; ni < 4; ni++) acc[mi][ni] = (f32x4){0.f, 0.f, 0.f, 0.f};

  float4 ga[4];
  uint4 gb[2];
  auto load_tile = [&](int k0) {
#pragma unroll
    for (int i = 0; i < 4; i++) {
      int f = t + 256 * i;
      int r = f >> 3, c4 = f & 7;
      int gr = row0 + r;
      if (gr >= N_NODES) gr = N_NODES - 1;
      ga[i] = *(const float4*)&x[(size_t)gr * F_IN + k0 + c4 * 4];
    }
#pragma unroll
    for (int i = 0; i < 2; i++) {
      int f = t + 256 * i;
      int r = f >> 2, c = f & 3;
      gb[i] = *(const uint4*)&WgT[r * F_IN + k0 + c * 8];
    }
  };

  load_tile(0);
#pragma unroll 1
  for (int kt = 0; kt < 16; kt++) {
    __syncthreads();
#pragma unroll
    for (int i = 0; i < 4; i++) {
      int f = t + 256 * i;
      int r = f >> 3, c4 = f & 7;
      unsigned int u0 = f2bf2(ga[i].x, ga[i].y);
      unsigned int u1 = f2bf2(ga[i].z, ga[i].w);
      *(uint2*)&As[r][c4 * 4] = make_uint2(u0, u1);
    }
#pragma unroll
    for (int i = 0; i < 2; i++) {
      int f = t + 256 * i;
      int r = f >> 2, c = f & 3;
      *(uint4*)&Bs[r][c * 8] = gb[i];
    }
    __syncthreads();
    if (kt < 15) load_tile((kt + 1) * 32);

    short8 afr[4], bfr[4];
#pragma unroll
    for (int mi = 0; mi < 4; mi++)
      afr[mi] = *(const short8*)&As[wm + mi * 16 + lane15][quad * 8];
#pragma unroll
    for (int ni = 0; ni < 4; ni++)
      bfr[ni] = *(const short8*)&Bs[wn + ni * 16 + lane15][quad * 8];
#pragma unroll
    for (int mi = 0; mi < 4; mi++)
#pragma unroll
      for (int ni = 0; ni < 4; ni++)
        acc[mi][ni] = __builtin_amdgcn_mfma_f32_16x16x32_bf16(
            bfr[ni], afr[mi], acc[mi][ni], 0, 0, 0);
  }

#pragma unroll
  for (int mi = 0; mi < 4; mi++) {
    int gm = row0 + wm + mi * 16 + lane15;
    if (gm < N_NODES) {
      float s = dinv[gm];
#pragma unroll
      for (int ni = 0; ni < 4; ni++) {
        int gn = wn + ni * 16 + quad * 4;
        unsigned int u0 = f2bf2(acc[mi][ni][0] * s, acc[mi][ni][1] * s);
        unsigned int u1 = f2bf2(acc[mi][ni][2] * s, acc[mi][ni][3] * s);
        *(uint2*)&sxw[(size_t)gm * F_GNN + gn] = make_uint2(u0, u1);
      }
    }
  }
}

// ---------- fused: edge-gather accumulate (LDS f32) + self-loop + ReLU + pool ----------
__global__ __launch_bounds__(512) void k_regagg(
    const unsigned int* __restrict__ pairs, const int* __restrict__ rbase,
    const unsigned short* __restrict__ sxw, const float* __restrict__ dinv,
    const float* __restrict__ bg, const int* __restrict__ batch,
    float* __restrict__ gx, float* __restrict__ gcnt) {
  __shared__ float acc[QTR][F_GNN];   // 64 KB -> 2 blocks/CU

  const int r = blockIdx.x >> 2;
  const int q = blockIdx.x & 3;       // quarter: dstl in [q*128, q*128+128)
  const int t = threadIdx.x;
  const int w = t >> 6, lane = t & 63;

  // zero accumulator
  float4* az = (float4*)acc;
#pragma unroll
  for (int i = 0; i < QTR * F_GNN / 4 / 512; i++)
    az[t + 512 * i] = make_float4(0.f, 0.f, 0.f, 0.f);
  __syncthreads();

  const int base = rbase[r];
  const int cnt = rbase[r + 1] - base;
  const unsigned int* S = (const unsigned int*)sxw;  // 2 bf16 per uint

  for (int i0 = w * 8; i0 < cnt; i0 += 64) {
    unsigned int pk[8], v[8];
    int dl[8];
    bool act[8];
#pragma unroll
    for (int j = 0; j < 8; j++) {
      int e = i0 + j;
      pk[j] = (e < cnt) ? pairs[base + e] : 0xFFFFFFFFu;
    }
#pragma unroll
    for (int j = 0; j < 8; j++) {
      dl[j] = (int)(pk[j] >> 17);
      act[j] = (pk[j] != 0xFFFFFFFFu) && ((dl[j] >> 7) == q);
      if (act[j]) v[j] = S[(size_t)(pk[j] & 0x1FFFFu) * 64 + lane];
    }
#pragma unroll
    for (int j = 0; j < 8; j++) {
      if (act[j]) {
        int n = dl[j] & 127;
        atomicAdd(&acc[n][2 * lane],     bf_lo(v[j]));
        atomicAdd(&acc[n][2 * lane + 1], bf_hi(v[j]));
      }
    }
  }
  __syncthreads();

  // epilogue: 128 nodes; wave w owns n = w, w+8, ... (16 nodes, increasing)
  const int node0 = (r << 9) + (q << 7);
  float2 b = ((const float2*)bg)[lane];
  int curg = -1;
  float psx = 0.f, psy = 0.f, pmx = 0.f, pmy = 0.f, pc = 0.f;

  for (int k = 0; k < 16; k += 4) {
    int nn[4], gg[4];
    unsigned int sv[4];
    float dv[4];
    bool na[4];
#pragma unroll
    for (int j = 0; j < 4; j++) {
      nn[j] = w + 8 * (k + j);
      int node = node0 + nn[j];
      na[j] = node < N_NODES;
      if (na[j]) {
        sv[j] = S[(size_t)node * 64 + lane];   // self-loop row
        gg[j] = batch[node];
        dv[j] = dinv[node];
      }
    }
#pragma unroll
    for (int j = 0; j < 4; j++) {
      if (!na[j]) continue;
      float ax = acc[nn[j]][2 * lane]     + bf_lo(sv[j]);
      float ay = acc[nn[j]][2 * lane + 1] + bf_hi(sv[j]);
      float rx = fmaxf(fmaf(ax, dv[j], b.x), 0.f);
      float ry = fmaxf(fmaf(ay, dv[j], b.y), 0.f);
      if (gg[j] != curg) {
        if (curg >= 0) {
          atomicAdd(&gx[curg * 256 + 2 * lane],     psx);
          atomicAdd(&gx[curg * 256 + 2 * lane + 1], psy);
          atomicMax((unsigned int*)&gx[curg * 256 + 128 + 2 * lane],
                    __float_as_uint(pmx));
          atomicMax((unsigned int*)&gx[curg * 256 + 129 + 2 * lane],
                    __float_as_uint(pmy));
          if (lane == 0) atomicAdd(&gcnt[curg], pc);
        }
        curg = gg[j];
        psx = psy = pmx = pmy = pc = 0.f;
      }
      psx += rx; psy += ry;
      pmx = fmaxf(pmx, rx); pmy = fmaxf(pmy, ry);
      pc += 1.f;
    }
  }
  if (curg >= 0) {
    atomicAdd(&gx[curg * 256 + 2 * lane],     psx);
    atomicAdd(&gx[curg * 256 + 2 * lane + 1], psy);
    atomicMax((unsigned int*)&gx[curg * 256 + 128 + 2 * lane], __float_as_uint(pmx));
    atomicMax((unsigned int*)&gx[curg * 256 + 129 + 2 * lane], __float_as_uint(pmy));
    if (lane == 0) atomicAdd(&gcnt[curg], pc);
  }
}

// ---------- encoder MLP + reparam + decoder MLP ----------
__global__ __launch_bounds__(64) void k_mlp(
    const float* __restrict__ gx, const float* __restrict__ gcnt,
    const float* __restrict__ eps,
    const float* __restrict__ We1, const float* __restrict__ be1,
    const float* __restrict__ We2, const float* __restrict__ be2,
    const float* __restrict__ We3, const float* __restrict__ be3,
    const float* __restrict__ Wd1, const float* __restrict__ bd1,
    const float* __restrict__ Wd2, const float* __restrict__ bd2,
    const float* __restrict__ Wd3, const float* __restrict__ bd3,
    float* __restrict__ out) {
  __shared__ float row[256];
  __shared__ float t1[64], t2[64], zz[64], d1[64], d2[64];
  int g = blockIdx.x;
  int j = threadIdx.x;

  float ic = 1.f / fmaxf(gcnt[g], 1.f);
#pragma unroll
  for (int i = 0; i < 4; i++) {
    float v = gx[g * 256 + j + 64 * i];
    if (i < 2) v *= ic;                 // mean = sum / cnt
    row[j + 64 * i] = v;
  }
  __syncthreads();

  float s = be1[j];
#pragma unroll 4
  for (int k = 0; k < 256; k++) s = fmaf(row[k], We1[k * 64 + j], s);
  t1[j] = eluf(s);
  __syncthreads();

  s = be2[j];
#pragma unroll 4
  for (int k = 0; k < 64; k++) s = fmaf(t1[k], We2[k * 64 + j], s);
  t2[j] = tanhf(s);
  __syncthreads();

  float m = be3[j], lv = be3[64 + j];
#pragma unroll 4
  for (int k = 0; k < 64; k++) {
    float tv = t2[k];
    m = fmaf(tv, We3[k * 128 + j], m);
    lv = fmaf(tv, We3[k * 128 + 64 + j], lv);
  }
  float sd = 1e-6f + softplusf(lv);
  float z = fmaf(eps[g * 64 + j], sd, m);
  out[g * 64 + j] = m;                  // mu
  out[32768 + g * 64 + j] = sd;         // stddev
  zz[j] = z;
  __syncthreads();

  s = bd1[j];
#pragma unroll 4
  for (int k = 0; k < 64; k++) s = fmaf(zz[k], Wd1[k * 64 + j], s);
  d1[j] = tanhf(s);
  __syncthreads();

  s = bd2[j];
#pragma unroll 4
  for (int k = 0; k < 64; k++) s = fmaf(d1[k], Wd2[k * 64 + j], s);
  d2[j] = eluf(s);
  __syncthreads();

  float y0 = bd3[j], y1 = bd3[64 + j];
#pragma unroll 4
  for (int k = 0; k < 64; k++) {
    float dv = d2[k];
    y0 = fmaf(dv, Wd3[k * 128 + j], y0);
    y1 = fmaf(dv, Wd3[k * 128 + 64 + j], y1);
  }
  y0 = fminf(fmaxf(sigmoidf(y0), 1e-8f), 1.f - 1e-8f);
  y1 = fminf(fmaxf(sigmoidf(y1), 1e-8f), 1.f - 1e-8f);
  out[65536 + g * 128 + j] = y0;
  out[65536 + g * 128 + 64 + j] = y1;
}

extern "C" void kernel_launch(void* const* d_in, const int* in_sizes, int n_in,
                              void* d_out, int out_size, void* d_ws, size_t ws_size,
                              hipStream_t stream) {
  const float* x     = (const float*)d_in[0];
  const int*   ei    = (const int*)d_in[1];
  const int*   batch = (const int*)d_in[2];
  const float* eps   = (const float*)d_in[3];
  const float* Wg    = (const float*)d_in[4];
  const float* bg    = (const float*)d_in[5];
  const float* We1   = (const float*)d_in[6];
  const float* be1   = (const float*)d_in[7];
  const float* We2   = (const float*)d_in[8];
  const float* be2   = (const float*)d_in[9];
  const float* We3   = (const float*)d_in[10];
  const float* be3   = (const float*)d_in[11];
  const float* Wd1   = (const float*)d_in[12];
  const float* bd1   = (const float*)d_in[13];
  const float* Wd2   = (const float*)d_in[14];
  const float* bd2   = (const float*)d_in[15];
  const float* Wd3   = (const float*)d_in[16];
  const float* bd3   = (const float*)d_in[17];
  float* out = (float*)d_out;

  // workspace layout (4B element offsets)
  int*            rbase = (int*)d_ws;                        // 256 (197 used)
  int*            rcnt  = rbase + 256;                       // 256 (doubles as cursor_r)
  int*            hist  = rcnt + 256;                        // 100352
  float*          dinv  = (float*)(hist + 100352);           // 100352
  unsigned int*   pairs = (unsigned int*)(dinv + 100352);    // 1600000
  unsigned short* WgT   = (unsigned short*)(pairs + 1600000);// 65536 bf16
  unsigned short* sxw   = WgT + 65536;                       // 12.8M bf16 (8B-aligned)
  float*          gx    = (float*)(sxw + 12800000);          // 131072
  float*          gcnt  = gx + 131072;                       // 512

  k_init<<<512, 256, 0, stream>>>(Wg, WgT, hist, gx, gcnt);
  k_hist<<<(N_EDGES + 1023) / 1024, 256, 0, stream>>>(ei, hist);
  k_rsum<<<N_REGIONS, 256, 0, stream>>>(hist, dinv, rcnt);
  k_rscan<<<1, 256, 0, stream>>>(rcnt, rbase);
  k_bucket<<<(N_EDGES + 4095) / 4096, 256, 0, stream>>>(ei, rcnt, pairs);
  k_gemm<<<(N_NODES + 127) / 128, 256, 0, stream>>>(x, WgT, dinv, sxw);
  k_regagg<<<N_REGIONS * 4, 512, 0, stream>>>(pairs, rbase, sxw, dinv, bg, batch,
                                              gx, gcnt);
  k_mlp<<<N_GRAPHS, 64, 0, stream>>>(gx, gcnt, eps, We1, be1, We2, be2, We3, be3,
                                     Wd1, bd1, Wd2, bd2, Wd3, bd3, out);
}

// Round 3
// 704.475 us; speedup vs baseline: 2.6188x; 2.6188x over previous
//
#include <hip/hip_runtime.h>
#include <hip/hip_bf16.h>
#include <math.h>

#define N_NODES 100000
#define N_EDGES 1600000
#define F_IN 512
#define F_GNN 128
#define HID 64
#define Z_DIM 64
#define N_GRAPHS 512
#define N_REGIONS 196      // 512 nodes per scan block

typedef __attribute__((ext_vector_type(8))) short short8;
typedef __attribute__((ext_vector_type(4))) float f32x4;

// ---------- small device helpers ----------
__device__ __forceinline__ float eluf(float v) { return v > 0.f ? v : expm1f(v); }
__device__ __forceinline__ float softplusf(float v) {
  return fmaxf(v, 0.f) + log1pf(expf(-fabsf(v)));
}
__device__ __forceinline__ float sigmoidf(float v) { return 1.f / (1.f + expf(-v)); }

__device__ __forceinline__ unsigned short f2bf(float f) {
  unsigned int u = __float_as_uint(f);
  u = (u + 0x7fffu + ((u >> 16) & 1u)) >> 16;
  return (unsigned short)u;
}
// packed f32x2 -> bf16x2 (low = a, high = b)
__device__ __forceinline__ unsigned int f2bf2(float a, float b) {
  __hip_bfloat162 h = __float22bfloat162_rn(make_float2(a, b));
  unsigned int u;
  __builtin_memcpy(&u, &h, 4);
  return u;
}
__device__ __forceinline__ float bf_lo(unsigned int u) { return __uint_as_float(u << 16); }
__device__ __forceinline__ float bf_hi(unsigned int u) { return __uint_as_float(u & 0xffff0000u); }

__device__ __forceinline__ int lower_bound_i(const int* __restrict__ a, int n, int v) {
  int lo = 0, hi = n;
  while (lo < hi) {
    int mid = (lo + hi) >> 1;
    if (a[mid] < v) lo = mid + 1; else hi = mid;
  }
  return lo;
}

// ---------- init: WgT transpose + zero hist ----------
__global__ __launch_bounds__(256) void k_init(
    const float* __restrict__ Wg, unsigned short* __restrict__ WgT,
    int* __restrict__ hist) {
  int i = blockIdx.x * 256 + threadIdx.x;   // 100352 threads
  if (i < 65536) {
    int n = i >> 9, k = i & 511;
    WgT[i] = f2bf(Wg[k * F_GNN + n]);
  }
  hist[i] = 0;
}

// ---------- per-node in-degree histogram (L2 global atomics) ----------
__global__ __launch_bounds__(256) void k_hist(const int* __restrict__ ei,
                                              int* __restrict__ hist) {
  int b = blockIdx.x, t = threadIdx.x;
#pragma unroll
  for (int j = 0; j < 4; j++) {
    int e = b * 1024 + t + 256 * j;
    if (e < N_EDGES) atomicAdd(&hist[ei[N_EDGES + e]], 1);
  }
}

// ---------- scan stage 1: per-block (512 nodes) exclusive scan ----------
__global__ __launch_bounds__(256) void k_scan1(const int* __restrict__ hist,
                                               int* __restrict__ off,
                                               int* __restrict__ bsum) {
  __shared__ int s[256];
  int b = blockIdx.x, t = threadIdx.x;
  int i0 = b * 512 + 2 * t;
  int a0 = (i0 < N_NODES) ? hist[i0] : 0;
  int a1 = (i0 + 1 < N_NODES) ? hist[i0 + 1] : 0;
  s[t] = a0 + a1;
  __syncthreads();
#pragma unroll
  for (int d = 1; d < 256; d <<= 1) {
    int v = (t >= d) ? s[t - d] : 0;
    __syncthreads();
    s[t] += v;
    __syncthreads();
  }
  int excl = (t > 0) ? s[t - 1] : 0;
  if (i0 < N_NODES) off[i0] = excl;
  if (i0 + 1 < N_NODES) off[i0 + 1] = excl + a0;
  if (t == 255) bsum[b] = s[255];
}

// ---------- scan stage 2: scan 196 block sums ----------
__global__ __launch_bounds__(256) void k_scan2(const int* __restrict__ bsum,
                                               int* __restrict__ boff) {
  __shared__ int s[256];
  int t = threadIdx.x;
  s[t] = (t < N_REGIONS) ? bsum[t] : 0;
  __syncthreads();
#pragma unroll
  for (int d = 1; d < 256; d <<= 1) {
    int v = (t >= d) ? s[t - d] : 0;
    __syncthreads();
    s[t] += v;
    __syncthreads();
  }
  boff[t] = (t > 0) ? s[t - 1] : 0;
}

// ---------- scan stage 3: finalize off, dinv, per-node scatter cursors ----------
__global__ __launch_bounds__(256) void k_scan3(int* __restrict__ off,
                                               const int* __restrict__ boff,
                                               const int* __restrict__ hist,
                                               float* __restrict__ dinv,
                                               int* __restrict__ cursor) {
  int i = blockIdx.x * 256 + threadIdx.x;
  if (i < N_NODES) {
    int o = off[i] + boff[i >> 9];
    off[i] = o;
    cursor[i] = o;
    dinv[i] = rsqrtf(1.0f + (float)hist[i]);
  }
  if (i == 0) off[N_NODES] = N_EDGES;
}

// ---------- direct CSR scatter: no LDS atomics, L2 atomics + scattered writes ----------
__global__ __launch_bounds__(256) void k_scatter(const int* __restrict__ ei,
                                                 int* __restrict__ cursor,
                                                 int* __restrict__ csr_src) {
  int b = blockIdx.x, t = threadIdx.x;
#pragma unroll
  for (int j = 0; j < 8; j++) {
    int e = b * 2048 + t + 256 * j;
    if (e < N_EDGES) {
      int dst = ei[N_EDGES + e];
      int pos = atomicAdd(&cursor[dst], 1);
      csr_src[pos] = ei[e];
    }
  }
}

// ---------- MFMA GEMM: sxw_bf16 = bf16((x @ Wg) * dinv[row]) ----------
__global__ __launch_bounds__(256) void k_gemm(
    const float* __restrict__ x, const unsigned short* __restrict__ WgT,
    const float* __restrict__ dinv, unsigned short* __restrict__ sxw) {
  __shared__ unsigned short As[128][32];   // [m][k] bf16
  __shared__ unsigned short Bs[128][32];   // [n][k] bf16 (B^T)

  const int t = threadIdx.x;
  const int lane15 = t & 15;
  const int quad = (t & 63) >> 4;
  const int wave = t >> 6;
  const int wm = (wave & 1) * 64;
  const int wn = (wave >> 1) * 64;
  const int row0 = blockIdx.x * 128;

  f32x4 acc[4][4];
#pragma unroll
  for (int mi = 0; mi < 4; mi++)
#pragma unroll
    for (int ni = 0; ni < 4; ni++) acc[mi][ni] = (f32x4){0.f, 0.f, 0.f, 0.f};

  float4 ga[4];
  uint4 gb[2];
  auto load_tile = [&](int k0) {
#pragma unroll
    for (int i = 0; i < 4; i++) {
      int f = t + 256 * i;
      int r = f >> 3, c4 = f & 7;
      int gr = row0 + r;
      if (gr >= N_NODES) gr = N_NODES - 1;
      ga[i] = *(const float4*)&x[(size_t)gr * F_IN + k0 + c4 * 4];
    }
#pragma unroll
    for (int i = 0; i < 2; i++) {
      int f = t + 256 * i;
      int r = f >> 2, c = f & 3;
      gb[i] = *(const uint4*)&WgT[r * F_IN + k0 + c * 8];
    }
  };

  load_tile(0);
#pragma unroll 1
  for (int kt = 0; kt < 16; kt++) {
    __syncthreads();
#pragma unroll
    for (int i = 0; i < 4; i++) {
      int f = t + 256 * i;
      int r = f >> 3, c4 = f & 7;
      unsigned int u0 = f2bf2(ga[i].x, ga[i].y);
      unsigned int u1 = f2bf2(ga[i].z, ga[i].w);
      *(uint2*)&As[r][c4 * 4] = make_uint2(u0, u1);
    }
#pragma unroll
    for (int i = 0; i < 2; i++) {
      int f = t + 256 * i;
      int r = f >> 2, c = f & 3;
      *(uint4*)&Bs[r][c * 8] = gb[i];
    }
    __syncthreads();
    if (kt < 15) load_tile((kt + 1) * 32);

    short8 afr[4], bfr[4];
#pragma unroll
    for (int mi = 0; mi < 4; mi++)
      afr[mi] = *(const short8*)&As[wm + mi * 16 + lane15][quad * 8];
#pragma unroll
    for (int ni = 0; ni < 4; ni++)
      bfr[ni] = *(const short8*)&Bs[wn + ni * 16 + lane15][quad * 8];
#pragma unroll
    for (int mi = 0; mi < 4; mi++)
#pragma unroll
      for (int ni = 0; ni < 4; ni++)
        acc[mi][ni] = __builtin_amdgcn_mfma_f32_16x16x32_bf16(
            bfr[ni], afr[mi], acc[mi][ni], 0, 0, 0);
  }

#pragma unroll
  for (int mi = 0; mi < 4; mi++) {
    int gm = row0 + wm + mi * 16 + lane15;
    if (gm < N_NODES) {
      float s = dinv[gm];
#pragma unroll
      for (int ni = 0; ni < 4; ni++) {
        int gn = wn + ni * 16 + quad * 4;
        unsigned int u0 = f2bf2(acc[mi][ni][0] * s, acc[mi][ni][1] * s);
        unsigned int u1 = f2bf2(acc[mi][ni][2] * s, acc[mi][ni][3] * s);
        *(uint2*)&sxw[(size_t)gm * F_GNN + gn] = make_uint2(u0, u1);
      }
    }
  }
}

// ---------- fused aggregate + ReLU + mean/max pool: one block per graph ----------
__global__ __launch_bounds__(1024) void k_aggpool(
    const unsigned short* __restrict__ sxw, const int* __restrict__ off,
    const int* __restrict__ csr_src, const float* __restrict__ dinv,
    const float* __restrict__ bg, const int* __restrict__ batch,
    float* __restrict__ gx) {
  __shared__ float2 ssum[16][64];
  __shared__ float2 smax[16][64];
  __shared__ int sse[2];
  const int g = blockIdx.x;
  const int t = threadIdx.x;
  const int wv = t >> 6;
  const int lane = t & 63;

  if (t == 0) sse[0] = lower_bound_i(batch, N_NODES, g);
  if (t == 64) sse[1] = lower_bound_i(batch, N_NODES, g + 1);
  __syncthreads();
  const int start = sse[0], end = sse[1];

  const unsigned int* S = (const unsigned int*)sxw;  // 2 bf16 per uint
  float2 b = ((const float2*)bg)[lane];
  float2 ps = make_float2(0.f, 0.f);
  float2 pm = make_float2(0.f, 0.f);

  for (int node = start + wv; node < end; node += 16) {
    unsigned int u = S[(size_t)node * 64 + lane];      // self-loop
    float sx = bf_lo(u), sy = bf_hi(u);
    int e = off[node];
    int e1 = off[node + 1];
    for (; e + 7 < e1; e += 8) {
      int s0 = csr_src[e + 0], s1 = csr_src[e + 1];
      int s2 = csr_src[e + 2], s3 = csr_src[e + 3];
      int s4 = csr_src[e + 4], s5 = csr_src[e + 5];
      int s6 = csr_src[e + 6], s7 = csr_src[e + 7];
      unsigned int v0 = S[(size_t)s0 * 64 + lane];
      unsigned int v1 = S[(size_t)s1 * 64 + lane];
      unsigned int v2 = S[(size_t)s2 * 64 + lane];
      unsigned int v3 = S[(size_t)s3 * 64 + lane];
      unsigned int v4 = S[(size_t)s4 * 64 + lane];
      unsigned int v5 = S[(size_t)s5 * 64 + lane];
      unsigned int v6 = S[(size_t)s6 * 64 + lane];
      unsigned int v7 = S[(size_t)s7 * 64 + lane];
      sx += bf_lo(v0) + bf_lo(v1) + bf_lo(v2) + bf_lo(v3)
          + bf_lo(v4) + bf_lo(v5) + bf_lo(v6) + bf_lo(v7);
      sy += bf_hi(v0) + bf_hi(v1) + bf_hi(v2) + bf_hi(v3)
          + bf_hi(v4) + bf_hi(v5) + bf_hi(v6) + bf_hi(v7);
    }
    for (; e < e1; e++) {
      unsigned int v0 = S[(size_t)csr_src[e] * 64 + lane];
      sx += bf_lo(v0);
      sy += bf_hi(v0);
    }
    float di = dinv[node];
    float rx = fmaxf(fmaf(sx, di, b.x), 0.f);
    float ry = fmaxf(fmaf(sy, di, b.y), 0.f);
    ps.x += rx; ps.y += ry;
    pm.x = fmaxf(pm.x, rx); pm.y = fmaxf(pm.y, ry);
  }

  ssum[wv][lane] = ps;
  smax[wv][lane] = pm;
  __syncthreads();
  if (t < 64) {
    float2 s = ssum[0][t];
    float2 m = smax[0][t];
#pragma unroll
    for (int h = 1; h < 16; h++) {
      s.x += ssum[h][t].x; s.y += ssum[h][t].y;
      m.x = fmaxf(m.x, smax[h][t].x); m.y = fmaxf(m.y, smax[h][t].y);
    }
    float ic = 1.f / fmaxf((float)(end - start), 1.f);
    gx[g * 256 + 2 * t] = s.x * ic;
    gx[g * 256 + 2 * t + 1] = s.y * ic;
    gx[g * 256 + 128 + 2 * t] = m.x;
    gx[g * 256 + 129 + 2 * t] = m.y;
  }
}

// ---------- encoder MLP + reparam + decoder MLP ----------
__global__ __launch_bounds__(64) void k_mlp(
    const float* __restrict__ gx, const float* __restrict__ eps,
    const float* __restrict__ We1, const float* __restrict__ be1,
    const float* __restrict__ We2, const float* __restrict__ be2,
    const float* __restrict__ We3, const float* __restrict__ be3,
    const float* __restrict__ Wd1, const float* __restrict__ bd1,
    const float* __restrict__ Wd2, const float* __restrict__ bd2,
    const float* __restrict__ Wd3, const float* __restrict__ bd3,
    float* __restrict__ out) {
  __shared__ float row[256];
  __shared__ float t1[64], t2[64], zz[64], d1[64], d2[64];
  int g = blockIdx.x;
  int j = threadIdx.x;

#pragma unroll
  for (int i = 0; i < 4; i++) row[j + 64 * i] = gx[g * 256 + j + 64 * i];
  __syncthreads();

  float s = be1[j];
#pragma unroll 4
  for (int k = 0; k < 256; k++) s = fmaf(row[k], We1[k * 64 + j], s);
  t1[j] = eluf(s);
  __syncthreads();

  s = be2[j];
#pragma unroll 4
  for (int k = 0; k < 64; k++) s = fmaf(t1[k], We2[k * 64 + j], s);
  t2[j] = tanhf(s);
  __syncthreads();

  float m = be3[j], lv = be3[64 + j];
#pragma unroll 4
  for (int k = 0; k < 64; k++) {
    float tv = t2[k];
    m = fmaf(tv, We3[k * 128 + j], m);
    lv = fmaf(tv, We3[k * 128 + 64 + j], lv);
  }
  float sd = 1e-6f + softplusf(lv);
  float z = fmaf(eps[g * 64 + j], sd, m);
  out[g * 64 + j] = m;                  // mu
  out[32768 + g * 64 + j] = sd;         // stddev
  zz[j] = z;
  __syncthreads();

  s = bd1[j];
#pragma unroll 4
  for (int k = 0; k < 64; k++) s = fmaf(zz[k], Wd1[k * 64 + j], s);
  d1[j] = tanhf(s);
  __syncthreads();

  s = bd2[j];
#pragma unroll 4
  for (int k = 0; k < 64; k++) s = fmaf(d1[k], Wd2[k * 64 + j], s);
  d2[j] = eluf(s);
  __syncthreads();

  float y0 = bd3[j], y1 = bd3[64 + j];
#pragma unroll 4
  for (int k = 0; k < 64; k++) {
    float dv = d2[k];
    y0 = fmaf(dv, Wd3[k * 128 + j], y0);
    y1 = fmaf(dv, Wd3[k * 128 + 64 + j], y1);
  }
  y0 = fminf(fmaxf(sigmoidf(y0), 1e-8f), 1.f - 1e-8f);
  y1 = fminf(fmaxf(sigmoidf(y1), 1e-8f), 1.f - 1e-8f);
  out[65536 + g * 128 + j] = y0;
  out[65536 + g * 128 + 64 + j] = y1;
}

extern "C" void kernel_launch(void* const* d_in, const int* in_sizes, int n_in,
                              void* d_out, int out_size, void* d_ws, size_t ws_size,
                              hipStream_t stream) {
  const float* x     = (const float*)d_in[0];
  const int*   ei    = (const int*)d_in[1];
  const int*   batch = (const int*)d_in[2];
  const float* eps   = (const float*)d_in[3];
  const float* Wg    = (const float*)d_in[4];
  const float* bg    = (const float*)d_in[5];
  const float* We1   = (const float*)d_in[6];
  const float* be1   = (const float*)d_in[7];
  const float* We2   = (const float*)d_in[8];
  const float* be2   = (const float*)d_in[9];
  const float* We3   = (const float*)d_in[10];
  const float* be3   = (const float*)d_in[11];
  const float* Wd1   = (const float*)d_in[12];
  const float* bd1   = (const float*)d_in[13];
  const float* Wd2   = (const float*)d_in[14];
  const float* bd2   = (const float*)d_in[15];
  const float* Wd3   = (const float*)d_in[16];
  const float* bd3   = (const float*)d_in[17];
  float* out = (float*)d_out;

  // workspace layout (4B element offsets)
  int*            hist    = (int*)d_ws;                       // 0      (100352)
  int*            off     = hist + 100352;                    // 100352 (100608; off[N] used)
  float*          dinv    = (float*)(off + 100608);           // 200960 (100352)
  int*            cursor  = (int*)(dinv + 100352);            // 301312 (100352)
  int*            bsum    = cursor + 100352;                  // 401664 (256)
  int*            boff    = bsum + 256;                       // 401920 (256)
  int*            csr_src = boff + 256;                       // 402176 (1600000)
  unsigned short* WgT     = (unsigned short*)(csr_src + 1600000);  // 65536 bf16 (16B-aligned)
  unsigned short* sxw     = WgT + 65536;                      // 12.8M bf16
  float*          gx      = (float*)(sxw + 12800000);         // 131072

  k_init<<<392, 256, 0, stream>>>(Wg, WgT, hist);
  k_hist<<<(N_EDGES + 1023) / 1024, 256, 0, stream>>>(ei, hist);
  k_scan1<<<N_REGIONS, 256, 0, stream>>>(hist, off, bsum);
  k_scan2<<<1, 256, 0, stream>>>(bsum, boff);
  k_scan3<<<392, 256, 0, stream>>>(off, boff, hist, dinv, cursor);
  k_scatter<<<(N_EDGES + 2047) / 2048, 256, 0, stream>>>(ei, cursor, csr_src);
  k_gemm<<<(N_NODES + 127) / 128, 256, 0, stream>>>(x, WgT, dinv, sxw);
  k_aggpool<<<N_GRAPHS, 1024, 0, stream>>>(sxw, off, csr_src, dinv, bg, batch, gx);
  k_mlp<<<N_GRAPHS, 64, 0, stream>>>(gx, eps, We1, be1, We2, be2, We3, be3,
                                     Wd1, bd1, Wd2, bd2, Wd3, bd3, out);
}

// Round 4
// 528.499 us; speedup vs baseline: 3.4908x; 1.3330x over previous
//
#include <hip/hip_runtime.h>
#include <hip/hip_bf16.h>
#include <math.h>

#define N_NODES 100000
#define N_EDGES 1600000
#define F_IN 512
#define F_GNN 128
#define HID 64
#define Z_DIM 64
#define N_GRAPHS 512
#define N_REGIONS 196      // 512 nodes per region
#define REGION_CAP 10240   // mean 8163, sd ~90 -> +22 sigma

typedef __attribute__((ext_vector_type(8))) short short8;
typedef __attribute__((ext_vector_type(4))) float f32x4;

// ---------- small device helpers ----------
__device__ __forceinline__ float eluf(float v) { return v > 0.f ? v : expm1f(v); }
__device__ __forceinline__ float softplusf(float v) {
  return fmaxf(v, 0.f) + log1pf(expf(-fabsf(v)));
}
__device__ __forceinline__ float sigmoidf(float v) { return 1.f / (1.f + expf(-v)); }

__device__ __forceinline__ unsigned short f2bf(float f) {
  unsigned int u = __float_as_uint(f);
  u = (u + 0x7fffu + ((u >> 16) & 1u)) >> 16;
  return (unsigned short)u;
}
// packed f32x2 -> bf16x2 (low = a, high = b)
__device__ __forceinline__ unsigned int f2bf2(float a, float b) {
  __hip_bfloat162 h = __float22bfloat162_rn(make_float2(a, b));
  unsigned int u;
  __builtin_memcpy(&u, &h, 4);
  return u;
}
__device__ __forceinline__ float bf_lo(unsigned int u) { return __uint_as_float(u << 16); }
__device__ __forceinline__ float bf_hi(unsigned int u) { return __uint_as_float(u & 0xffff0000u); }

__device__ __forceinline__ int lower_bound_i(const int* __restrict__ a, int n, int v) {
  int lo = 0, hi = n;
  while (lo < hi) {
    int mid = (lo + hi) >> 1;
    if (a[mid] < v) lo = mid + 1; else hi = mid;
  }
  return lo;
}

// ---------- zero the 196 region counters ----------
__global__ __launch_bounds__(256) void k_z(int* __restrict__ rcnt) {
  rcnt[threadIdx.x] = 0;
}

// ---------- region counts (196 counters, LDS-staged) + WgT transpose fused ----------
__global__ __launch_bounds__(256) void k_rcount(
    const int* __restrict__ ei, int* __restrict__ rcnt,
    const float* __restrict__ Wg, unsigned short* __restrict__ WgT) {
  __shared__ int lh[256];
  const int b = blockIdx.x, t = threadIdx.x;
  if (b < 256) {                       // fused WgT transpose (65536 elems)
    int i = b * 256 + t;
    int n = i >> 9, k = i & 511;
    WgT[i] = f2bf(Wg[k * F_GNN + n]);
  }
  lh[t] = 0;
  __syncthreads();
#pragma unroll
  for (int jj = 0; jj < 4; jj++) {
    int e = b * 4096 + jj * 1024 + 4 * t;
    if (e < N_EDGES) {
      int4 d4 = *(const int4*)&ei[N_EDGES + e];
      atomicAdd(&lh[d4.x >> 9], 1);
      atomicAdd(&lh[d4.y >> 9], 1);
      atomicAdd(&lh[d4.z >> 9], 1);
      atomicAdd(&lh[d4.w >> 9], 1);
    }
  }
  __syncthreads();
  if (t < N_REGIONS && lh[t] > 0) atomicAdd(&rcnt[t], lh[t]);
}

// ---------- scan 196 region counts -> rbase (excl) + seed cursors ----------
__global__ __launch_bounds__(256) void k_rscan(int* __restrict__ rcnt,  // == cursor_r
                                               int* __restrict__ rbase) {
  __shared__ int s[256];
  int t = threadIdx.x;
  s[t] = (t < N_REGIONS) ? rcnt[t] : 0;
  __syncthreads();
#pragma unroll
  for (int d = 1; d < 256; d <<= 1) {
    int v = (t >= d) ? s[t - d] : 0;
    __syncthreads();
    s[t] += v;
    __syncthreads();
  }
  int excl = (t > 0) ? s[t - 1] : 0;
  rbase[t] = excl;
  rcnt[t] = excl;               // cursor seed
  if (t == 255) rbase[N_REGIONS] = s[255];   // = N_EDGES
}

// ---------- pass 1: bucket edges into 196 regions, LDS-staged ----------
__global__ __launch_bounds__(512) void k_bucket(
    const int* __restrict__ ei, int* __restrict__ cursor_r,
    uint2* __restrict__ pairs) {
  __shared__ int lhist[256];
  __shared__ int lofs[256];
  __shared__ int lcur[256];
  __shared__ int gbase[256];
  __shared__ int sc[256];
  __shared__ uint2 lpairs[4096];   // 32 KB

  const int b = blockIdx.x, t = threadIdx.x;
  const int e0 = b * 4096;
  const int n_b = min(4096, N_EDGES - e0);

  if (t < 256) { lhist[t] = 0; lcur[t] = 0; }
  __syncthreads();

  int srcv[8], dstv[8];
#pragma unroll
  for (int jj = 0; jj < 2; jj++) {
    int e = e0 + jj * 2048 + 4 * t;
    if (e < N_EDGES) {
      int4 s4 = *(const int4*)&ei[e];
      int4 d4 = *(const int4*)&ei[N_EDGES + e];
      srcv[4 * jj + 0] = s4.x; dstv[4 * jj + 0] = d4.x;
      srcv[4 * jj + 1] = s4.y; dstv[4 * jj + 1] = d4.y;
      srcv[4 * jj + 2] = s4.z; dstv[4 * jj + 2] = d4.z;
      srcv[4 * jj + 3] = s4.w; dstv[4 * jj + 3] = d4.w;
      atomicAdd(&lhist[d4.x >> 9], 1);
      atomicAdd(&lhist[d4.y >> 9], 1);
      atomicAdd(&lhist[d4.z >> 9], 1);
      atomicAdd(&lhist[d4.w >> 9], 1);
    } else {
      dstv[4 * jj + 0] = dstv[4 * jj + 1] = dstv[4 * jj + 2] = dstv[4 * jj + 3] = -1;
    }
  }
  __syncthreads();

  // exclusive scan of lhist -> lofs (first 256 threads)
  if (t < 256) sc[t] = lhist[t];
  __syncthreads();
#pragma unroll
  for (int d = 1; d < 256; d <<= 1) {
    int v = (t < 256 && t >= d) ? sc[t - d] : 0;
    __syncthreads();
    if (t < 256) sc[t] += v;
    __syncthreads();
  }
  if (t < 256) lofs[t] = (t > 0) ? sc[t - 1] : 0;
  if (t < N_REGIONS && lhist[t] > 0) gbase[t] = atomicAdd(&cursor_r[t], lhist[t]);
  __syncthreads();

  // local scatter into LDS, region-contiguous
#pragma unroll
  for (int j = 0; j < 8; j++) {
    if (dstv[j] >= 0) {
      int r = dstv[j] >> 9;
      int pos = lofs[r] + atomicAdd(&lcur[r], 1);
      lpairs[pos] = make_uint2((unsigned)srcv[j], (unsigned)dstv[j]);
    }
  }
  __syncthreads();

  // flush: consecutive i -> consecutive slot within region run (coalesced)
  for (int i = t; i < n_b; i += 512) {
    int lo = 0, hi = N_REGIONS;
    while (hi - lo > 1) {
      int mid = (lo + hi) >> 1;
      if (lofs[mid] <= i) lo = mid; else hi = mid;
    }
    pairs[gbase[lo] + (i - lofs[lo])] = lpairs[i];
  }
}

// ---------- pass 2: per-region hist + scan -> off/dinv, counting sort -> csr_src ----------
__global__ __launch_bounds__(512) void k_region(
    const uint2* __restrict__ pairs, const int* __restrict__ rbase,
    int* __restrict__ off, float* __restrict__ dinv, int* __restrict__ csr_src) {
  __shared__ int nh[512];
  __shared__ int sofs[512];
  __shared__ int s[512];
  __shared__ int ncur[512];
  __shared__ int cbuf[REGION_CAP];   // 40 KB

  const int r = blockIdx.x, t = threadIdx.x;
  const int base = rbase[r];
  const int cnt = rbase[r + 1] - base;

  nh[t] = 0;
  ncur[t] = 0;
  __syncthreads();

  for (int i = t; i < cnt; i += 512) {
    uint2 p = pairs[base + i];
    atomicAdd(&nh[p.y & 511], 1);
  }
  __syncthreads();

  // inclusive scan of 512 counts
  int a = nh[t];
  s[t] = a;
  __syncthreads();
#pragma unroll
  for (int d = 1; d < 512; d <<= 1) {
    int v = (t >= d) ? s[t - d] : 0;
    __syncthreads();
    s[t] += v;
    __syncthreads();
  }
  int excl = (t > 0) ? s[t - 1] : 0;
  sofs[t] = excl;

  // write off + dinv for this region's nodes
  const int node = (r << 9) + t;
  if (node < N_NODES) {
    off[node] = base + excl;
    dinv[node] = rsqrtf(1.f + (float)a);
  }
  if (r == N_REGIONS - 1 && t == 0) off[N_NODES] = N_EDGES;
  __syncthreads();

  // counting sort into LDS (pairs slice is cache-hot)
  for (int i = t; i < cnt; i += 512) {
    uint2 p = pairs[base + i];
    int d = (int)p.y & 511;
    int lpos = sofs[d] + atomicAdd(&ncur[d], 1);
    if (lpos < REGION_CAP) cbuf[lpos] = (int)p.x;
  }
  __syncthreads();
  for (int i = t; i < cnt; i += 512) csr_src[base + i] = cbuf[i];
}

// ---------- MFMA GEMM: sxw_bf16 = bf16((x @ Wg) * dinv[row]) ----------
__global__ __launch_bounds__(256) void k_gemm(
    const float* __restrict__ x, const unsigned short* __restrict__ WgT,
    const float* __restrict__ dinv, unsigned short* __restrict__ sxw) {
  __shared__ unsigned short As[128][32];   // [m][k] bf16
  __shared__ unsigned short Bs[128][32];   // [n][k] bf16 (B^T)

  const int t = threadIdx.x;
  const int lane15 = t & 15;
  const int quad = (t & 63) >> 4;
  const int wave = t >> 6;
  const int wm = (wave & 1) * 64;
  const int wn = (wave >> 1) * 64;
  const int row0 = blockIdx.x * 128;

  f32x4 acc[4][4];
#pragma unroll
  for (int mi = 0; mi < 4; mi++)
#pragma unroll
    for (int ni = 0; ni < 4; ni++) acc[mi][ni] = (f32x4){0.f, 0.f, 0.f, 0.f};

  float4 ga[4];
  uint4 gb[2];
  auto load_tile = [&](int k0) {
#pragma unroll
    for (int i = 0; i < 4; i++) {
      int f = t + 256 * i;
      int r = f >> 3, c4 = f & 7;
      int gr = row0 + r;
      if (gr >= N_NODES) gr = N_NODES - 1;
      ga[i] = *(const float4*)&x[(size_t)gr * F_IN + k0 + c4 * 4];
    }
#pragma unroll
    for (int i = 0; i < 2; i++) {
      int f = t + 256 * i;
      int r = f >> 2, c = f & 3;
      gb[i] = *(const uint4*)&WgT[r * F_IN + k0 + c * 8];
    }
  };

  load_tile(0);
#pragma unroll 1
  for (int kt = 0; kt < 16; kt++) {
    __syncthreads();
#pragma unroll
    for (int i = 0; i < 4; i++) {
      int f = t + 256 * i;
      int r = f >> 3, c4 = f & 7;
      unsigned int u0 = f2bf2(ga[i].x, ga[i].y);
      unsigned int u1 = f2bf2(ga[i].z, ga[i].w);
      *(uint2*)&As[r][c4 * 4] = make_uint2(u0, u1);
    }
#pragma unroll
    for (int i = 0; i < 2; i++) {
      int f = t + 256 * i;
      int r = f >> 2, c = f & 3;
      *(uint4*)&Bs[r][c * 8] = gb[i];
    }
    __syncthreads();
    if (kt < 15) load_tile((kt + 1) * 32);

    short8 afr[4], bfr[4];
#pragma unroll
    for (int mi = 0; mi < 4; mi++)
      afr[mi] = *(const short8*)&As[wm + mi * 16 + lane15][quad * 8];
#pragma unroll
    for (int ni = 0; ni < 4; ni++)
      bfr[ni] = *(const short8*)&Bs[wn + ni * 16 + lane15][quad * 8];
#pragma unroll
    for (int mi = 0; mi < 4; mi++)
#pragma unroll
      for (int ni = 0; ni < 4; ni++)
        acc[mi][ni] = __builtin_amdgcn_mfma_f32_16x16x32_bf16(
            bfr[ni], afr[mi], acc[mi][ni], 0, 0, 0);
  }

#pragma unroll
  for (int mi = 0; mi < 4; mi++) {
    int gm = row0 + wm + mi * 16 + lane15;
    if (gm < N_NODES) {
      float s = dinv[gm];
#pragma unroll
      for (int ni = 0; ni < 4; ni++) {
        int gn = wn + ni * 16 + quad * 4;
        unsigned int u0 = f2bf2(acc[mi][ni][0] * s, acc[mi][ni][1] * s);
        unsigned int u1 = f2bf2(acc[mi][ni][2] * s, acc[mi][ni][3] * s);
        *(uint2*)&sxw[(size_t)gm * F_GNN + gn] = make_uint2(u0, u1);
      }
    }
  }
}

// ---------- fused aggregate + ReLU + mean/max pool: one block per graph ----------
// uint2 gather: 64-lane wave fetches 2 rows per load inst (h = lane>>5 picks edge)
__global__ __launch_bounds__(1024) void k_aggpool(
    const unsigned short* __restrict__ sxw, const int* __restrict__ off,
    const int* __restrict__ csr_src, const float* __restrict__ dinv,
    const float* __restrict__ bg, const int* __restrict__ batch,
    float* __restrict__ gx) {
  __shared__ float4 ssum[16][32];
  __shared__ float4 smax[16][32];
  __shared__ int sse[2];
  const int g = blockIdx.x;
  const int t = threadIdx.x;
  const int wv = t >> 6;
  const int lane = t & 63;
  const int h = lane >> 5;      // which edge of the pair
  const int c = lane & 31;      // 8B feature chunk (4 bf16)

  if (t == 0) sse[0] = lower_bound_i(batch, N_NODES, g);
  if (t == 64) sse[1] = lower_bound_i(batch, N_NODES, g + 1);
  __syncthreads();
  const int start = sse[0], end = sse[1];

  const uint2* S2 = (const uint2*)sxw;  // 4 bf16 per uint2, row = 32 uint2
  float4 bb = ((const float4*)bg)[c];
  float ps0 = 0.f, ps1 = 0.f, ps2 = 0.f, ps3 = 0.f;
  float pm0 = 0.f, pm1 = 0.f, pm2 = 0.f, pm3 = 0.f;

  for (int node = start + wv; node < end; node += 16) {
    float sx0 = 0.f, sx1 = 0.f, sx2 = 0.f, sx3 = 0.f;
    int e = off[node];
    const int e1 = off[node + 1];
    for (; e + 7 < e1; e += 8) {
      int s0 = csr_src[e + 0], s1 = csr_src[e + 1];
      int s2 = csr_src[e + 2], s3 = csr_src[e + 3];
      int s4 = csr_src[e + 4], s5 = csr_src[e + 5];
      int s6 = csr_src[e + 6], s7 = csr_src[e + 7];
      uint2 v0 = S2[(size_t)(h ? s1 : s0) * 32 + c];
      uint2 v1 = S2[(size_t)(h ? s3 : s2) * 32 + c];
      uint2 v2 = S2[(size_t)(h ? s5 : s4) * 32 + c];
      uint2 v3 = S2[(size_t)(h ? s7 : s6) * 32 + c];
      sx0 += bf_lo(v0.x) + bf_lo(v1.x) + bf_lo(v2.x) + bf_lo(v3.x);
      sx1 += bf_hi(v0.x) + bf_hi(v1.x) + bf_hi(v2.x) + bf_hi(v3.x);
      sx2 += bf_lo(v0.y) + bf_lo(v1.y) + bf_lo(v2.y) + bf_lo(v3.y);
      sx3 += bf_hi(v0.y) + bf_hi(v1.y) + bf_hi(v2.y) + bf_hi(v3.y);
    }
    for (; e + 1 < e1; e += 2) {
      int sa = csr_src[e], sb = csr_src[e + 1];
      uint2 v = S2[(size_t)(h ? sb : sa) * 32 + c];
      sx0 += bf_lo(v.x); sx1 += bf_hi(v.x);
      sx2 += bf_lo(v.y); sx3 += bf_hi(v.y);
    }
    if (e < e1 && h == 0) {
      uint2 v = S2[(size_t)csr_src[e] * 32 + c];
      sx0 += bf_lo(v.x); sx1 += bf_hi(v.x);
      sx2 += bf_lo(v.y); sx3 += bf_hi(v.y);
    }
    // combine the two half-wave edge partials
    sx0 += __shfl_xor(sx0, 32);
    sx1 += __shfl_xor(sx1, 32);
    sx2 += __shfl_xor(sx2, 32);
    sx3 += __shfl_xor(sx3, 32);
    // self-loop row
    uint2 sv = S2[(size_t)node * 32 + c];
    sx0 += bf_lo(sv.x); sx1 += bf_hi(sv.x);
    sx2 += bf_lo(sv.y); sx3 += bf_hi(sv.y);

    float di = dinv[node];
    float r0 = fmaxf(fmaf(sx0, di, bb.x), 0.f);
    float r1 = fmaxf(fmaf(sx1, di, bb.y), 0.f);
    float r2 = fmaxf(fmaf(sx2, di, bb.z), 0.f);
    float r3 = fmaxf(fmaf(sx3, di, bb.w), 0.f);
    ps0 += r0; ps1 += r1; ps2 += r2; ps3 += r3;
    pm0 = fmaxf(pm0, r0); pm1 = fmaxf(pm1, r1);
    pm2 = fmaxf(pm2, r2); pm3 = fmaxf(pm3, r3);
  }

  if (h == 0) {
    ssum[wv][c] = make_float4(ps0, ps1, ps2, ps3);
    smax[wv][c] = make_float4(pm0, pm1, pm2, pm3);
  }
  __syncthreads();
  if (t < 32) {
    float4 s = ssum[0][t];
    float4 m = smax[0][t];
#pragma unroll
    for (int hh = 1; hh < 16; hh++) {
      float4 a = ssum[hh][t], b2 = smax[hh][t];
      s.x += a.x; s.y += a.y; s.z += a.z; s.w += a.w;
      m.x = fmaxf(m.x, b2.x); m.y = fmaxf(m.y, b2.y);
      m.z = fmaxf(m.z, b2.z); m.w = fmaxf(m.w, b2.w);
    }
    float ic = 1.f / fmaxf((float)(end - start), 1.f);
    gx[g * 256 + 4 * t + 0] = s.x * ic;
    gx[g * 256 + 4 * t + 1] = s.y * ic;
    gx[g * 256 + 4 * t + 2] = s.z * ic;
    gx[g * 256 + 4 * t + 3] = s.w * ic;
    gx[g * 256 + 128 + 4 * t + 0] = m.x;
    gx[g * 256 + 128 + 4 * t + 1] = m.y;
    gx[g * 256 + 128 + 4 * t + 2] = m.z;
    gx[g * 256 + 128 + 4 * t + 3] = m.w;
  }
}

// ---------- encoder MLP + reparam + decoder MLP ----------
__global__ __launch_bounds__(64) void k_mlp(
    const float* __restrict__ gx, const float* __restrict__ eps,
    const float* __restrict__ We1, const float* __restrict__ be1,
    const float* __restrict__ We2, const float* __restrict__ be2,
    const float* __restrict__ We3, const float* __restrict__ be3,
    const float* __restrict__ Wd1, const float* __restrict__ bd1,
    const float* __restrict__ Wd2, const float* __restrict__ bd2,
    const float* __restrict__ Wd3, const float* __restrict__ bd3,
    float* __restrict__ out) {
  __shared__ float row[256];
  __shared__ float t1[64], t2[64], zz[64], d1[64], d2[64];
  int g = blockIdx.x;
  int j = threadIdx.x;

#pragma unroll
  for (int i = 0; i < 4; i++) row[j + 64 * i] = gx[g * 256 + j + 64 * i];
  __syncthreads();

  float s = be1[j];
#pragma unroll 4
  for (int k = 0; k < 256; k++) s = fmaf(row[k], We1[k * 64 + j], s);
  t1[j] = eluf(s);
  __syncthreads();

  s = be2[j];
#pragma unroll 4
  for (int k = 0; k < 64; k++) s = fmaf(t1[k], We2[k * 64 + j], s);
  t2[j] = tanhf(s);
  __syncthreads();

  float m = be3[j], lv = be3[64 + j];
#pragma unroll 4
  for (int k = 0; k < 64; k++) {
    float tv = t2[k];
    m = fmaf(tv, We3[k * 128 + j], m);
    lv = fmaf(tv, We3[k * 128 + 64 + j], lv);
  }
  float sd = 1e-6f + softplusf(lv);
  float z = fmaf(eps[g * 64 + j], sd, m);
  out[g * 64 + j] = m;                  // mu
  out[32768 + g * 64 + j] = sd;         // stddev
  zz[j] = z;
  __syncthreads();

  s = bd1[j];
#pragma unroll 4
  for (int k = 0; k < 64; k++) s = fmaf(zz[k], Wd1[k * 64 + j], s);
  d1[j] = tanhf(s);
  __syncthreads();

  s = bd2[j];
#pragma unroll 4
  for (int k = 0; k < 64; k++) s = fmaf(d1[k], Wd2[k * 64 + j], s);
  d2[j] = eluf(s);
  __syncthreads();

  float y0 = bd3[j], y1 = bd3[64 + j];
#pragma unroll 4
  for (int k = 0; k < 64; k++) {
    float dv = d2[k];
    y0 = fmaf(dv, Wd3[k * 128 + j], y0);
    y1 = fmaf(dv, Wd3[k * 128 + 64 + j], y1);
  }
  y0 = fminf(fmaxf(sigmoidf(y0), 1e-8f), 1.f - 1e-8f);
  y1 = fminf(fmaxf(sigmoidf(y1), 1e-8f), 1.f - 1e-8f);
  out[65536 + g * 128 + j] = y0;
  out[65536 + g * 128 + 64 + j] = y1;
}

extern "C" void kernel_launch(void* const* d_in, const int* in_sizes, int n_in,
                              void* d_out, int out_size, void* d_ws, size_t ws_size,
                              hipStream_t stream) {
  const float* x     = (const float*)d_in[0];
  const int*   ei    = (const int*)d_in[1];
  const int*   batch = (const int*)d_in[2];
  const float* eps   = (const float*)d_in[3];
  const float* Wg    = (const float*)d_in[4];
  const float* bg    = (const float*)d_in[5];
  const float* We1   = (const float*)d_in[6];
  const float* be1   = (const float*)d_in[7];
  const float* We2   = (const float*)d_in[8];
  const float* be2   = (const float*)d_in[9];
  const float* We3   = (const float*)d_in[10];
  const float* be3   = (const float*)d_in[11];
  const float* Wd1   = (const float*)d_in[12];
  const float* bd1   = (const float*)d_in[13];
  const float* Wd2   = (const float*)d_in[14];
  const float* bd2   = (const float*)d_in[15];
  const float* Wd3   = (const float*)d_in[16];
  const float* bd3   = (const float*)d_in[17];
  float* out = (float*)d_out;

  // workspace layout (4B element offsets)
  int*            rbase   = (int*)d_ws;                       // 256 (197 used)
  int*            rcnt    = rbase + 256;                      // 256 (doubles as cursor_r)
  int*            off     = rcnt + 256;                       // 100608 (100001 used)
  float*          dinv    = (float*)(off + 100608);           // 100352
  int*            csr_src = (int*)(dinv + 100352);            // 1600000
  uint2*          pairs   = (uint2*)(csr_src + 1600000);      // 1.6M uint2 (8B-aligned)
  unsigned short* WgT     = (unsigned short*)(pairs + 1600000);  // 65536 bf16
  unsigned short* sxw     = WgT + 65536;                      // 12.8M bf16
  float*          gx      = (float*)(sxw + 12800000);         // 131072

  k_z<<<1, 256, 0, stream>>>(rcnt);
  k_rcount<<<(N_EDGES + 4095) / 4096, 256, 0, stream>>>(ei, rcnt, Wg, WgT);
  k_rscan<<<1, 256, 0, stream>>>(rcnt, rbase);
  k_bucket<<<(N_EDGES + 4095) / 4096, 512, 0, stream>>>(ei, rcnt, pairs);
  k_region<<<N_REGIONS, 512, 0, stream>>>(pairs, rbase, off, dinv, csr_src);
  k_gemm<<<(N_NODES + 127) / 128, 256, 0, stream>>>(x, WgT, dinv, sxw);
  k_aggpool<<<N_GRAPHS, 1024, 0, stream>>>(sxw, off, csr_src, dinv, bg, batch, gx);
  k_mlp<<<N_GRAPHS, 64, 0, stream>>>(gx, eps, We1, be1, We2, be2, We3, be3,
                                     Wd1, bd1, Wd2, bd2, Wd3, bd3, out);
}

// Round 5
// 509.711 us; speedup vs baseline: 3.6195x; 1.0369x over previous
//
#include <hip/hip_runtime.h>
#include <hip/hip_bf16.h>
#include <math.h>

#define N_NODES 100000
#define N_EDGES 1600000
#define F_IN 512
#define F_GNN 128
#define HID 64
#define Z_DIM 64
#define N_GRAPHS 512
#define N_REGIONS 196      // 512 nodes per region
#define REGION_CAP 10240   // slab size; mean 8163, sd ~90 -> +22 sigma

typedef __attribute__((ext_vector_type(8))) short short8;
typedef __attribute__((ext_vector_type(4))) float f32x4;

// ---------- small device helpers ----------
__device__ __forceinline__ float eluf(float v) { return v > 0.f ? v : expm1f(v); }
__device__ __forceinline__ float softplusf(float v) {
  return fmaxf(v, 0.f) + log1pf(expf(-fabsf(v)));
}
__device__ __forceinline__ float sigmoidf(float v) { return 1.f / (1.f + expf(-v)); }

__device__ __forceinline__ unsigned short f2bf(float f) {
  unsigned int u = __float_as_uint(f);
  u = (u + 0x7fffu + ((u >> 16) & 1u)) >> 16;
  return (unsigned short)u;
}
// packed f32x2 -> bf16x2 (low = a, high = b)
__device__ __forceinline__ unsigned int f2bf2(float a, float b) {
  __hip_bfloat162 h = __float22bfloat162_rn(make_float2(a, b));
  unsigned int u;
  __builtin_memcpy(&u, &h, 4);
  return u;
}
__device__ __forceinline__ float bf_lo(unsigned int u) { return __uint_as_float(u << 16); }
__device__ __forceinline__ float bf_hi(unsigned int u) { return __uint_as_float(u & 0xffff0000u); }

__device__ __forceinline__ int lower_bound_i(const int* __restrict__ a, int n, int v) {
  int lo = 0, hi = n;
  while (lo < hi) {
    int mid = (lo + hi) >> 1;
    if (a[mid] < v) lo = mid + 1; else hi = mid;
  }
  return lo;
}

// ---------- init: WgT transpose + seed region cursors at slab bases ----------
__global__ __launch_bounds__(256) void k_init(
    const float* __restrict__ Wg, unsigned short* __restrict__ WgT,
    int* __restrict__ cursor) {
  int i = blockIdx.x * 256 + threadIdx.x;   // 65536 total
  int n = i >> 9, k = i & 511;
  WgT[i] = f2bf(Wg[k * F_GNN + n]);
  if (i < 256) cursor[i] = i * REGION_CAP;
}

// ---------- pass 1: bucket edges into 196 fixed-capacity slabs, packed 4B ----------
__global__ __launch_bounds__(512) void k_bucket(
    const int* __restrict__ ei, int* __restrict__ cursor_r,
    unsigned int* __restrict__ pairs) {
  __shared__ int lhist[256];
  __shared__ int lofs[256];
  __shared__ int lcur[256];
  __shared__ int gbase[256];
  __shared__ int sc[256];
  __shared__ unsigned int lpairs[4096];   // 16 KB

  const int b = blockIdx.x, t = threadIdx.x;
  const int e0 = b * 4096;
  const int n_b = min(4096, N_EDGES - e0);

  if (t < 256) { lhist[t] = 0; lcur[t] = 0; }
  __syncthreads();

  int srcv[8], dstv[8];
#pragma unroll
  for (int jj = 0; jj < 2; jj++) {
    int e = e0 + jj * 2048 + 4 * t;
    if (e < N_EDGES) {
      int4 s4 = *(const int4*)&ei[e];
      int4 d4 = *(const int4*)&ei[N_EDGES + e];
      srcv[4 * jj + 0] = s4.x; dstv[4 * jj + 0] = d4.x;
      srcv[4 * jj + 1] = s4.y; dstv[4 * jj + 1] = d4.y;
      srcv[4 * jj + 2] = s4.z; dstv[4 * jj + 2] = d4.z;
      srcv[4 * jj + 3] = s4.w; dstv[4 * jj + 3] = d4.w;
      atomicAdd(&lhist[d4.x >> 9], 1);
      atomicAdd(&lhist[d4.y >> 9], 1);
      atomicAdd(&lhist[d4.z >> 9], 1);
      atomicAdd(&lhist[d4.w >> 9], 1);
    } else {
      dstv[4 * jj + 0] = dstv[4 * jj + 1] = dstv[4 * jj + 2] = dstv[4 * jj + 3] = -1;
    }
  }
  __syncthreads();

  // exclusive scan of lhist -> lofs (first 256 threads)
  if (t < 256) sc[t] = lhist[t];
  __syncthreads();
#pragma unroll
  for (int d = 1; d < 256; d <<= 1) {
    int v = (t < 256 && t >= d) ? sc[t - d] : 0;
    __syncthreads();
    if (t < 256) sc[t] += v;
    __syncthreads();
  }
  if (t < 256) lofs[t] = (t > 0) ? sc[t - 1] : 0;
  if (t < N_REGIONS && lhist[t] > 0) gbase[t] = atomicAdd(&cursor_r[t], lhist[t]);
  __syncthreads();

  // local scatter into LDS, region-contiguous, packed (src 17b | dstl 9b << 17)
#pragma unroll
  for (int j = 0; j < 8; j++) {
    if (dstv[j] >= 0) {
      int r = dstv[j] >> 9;
      int pos = lofs[r] + atomicAdd(&lcur[r], 1);
      lpairs[pos] = (unsigned)srcv[j] | ((unsigned)(dstv[j] & 511) << 17);
    }
  }
  __syncthreads();

  // flush: consecutive i -> consecutive slot within region run (coalesced)
  for (int i = t; i < n_b; i += 512) {
    int lo = 0, hi = N_REGIONS;
    while (hi - lo > 1) {
      int mid = (lo + hi) >> 1;
      if (lofs[mid] <= i) lo = mid; else hi = mid;
    }
    pairs[gbase[lo] + (i - lofs[lo])] = lpairs[i];
  }
}

// ---------- pass 2: per-region hist + scan -> off/dinv, counting sort -> csr_src ----------
__global__ __launch_bounds__(1024) void k_region(
    const unsigned int* __restrict__ pairs, const int* __restrict__ cursor,
    int* __restrict__ off, float* __restrict__ dinv, int* __restrict__ csr_src) {
  __shared__ int nh[512];
  __shared__ int sofs[512];
  __shared__ int s[512];
  __shared__ int ncur[512];
  __shared__ int cbuf[REGION_CAP];   // 40 KB

  const int r = blockIdx.x, t = threadIdx.x;
  const int base = r * REGION_CAP;
  const int cnt = cursor[r] - base;

  if (t < 512) { nh[t] = 0; ncur[t] = 0; }
  __syncthreads();

  for (int i = t; i < cnt; i += 1024)
    atomicAdd(&nh[(pairs[base + i] >> 17) & 511], 1);
  __syncthreads();

  // inclusive scan of 512 counts (first 512 threads)
  int a = (t < 512) ? nh[t] : 0;
  if (t < 512) s[t] = a;
  __syncthreads();
#pragma unroll
  for (int d = 1; d < 512; d <<= 1) {
    int v = (t < 512 && t >= d) ? s[t - d] : 0;
    __syncthreads();
    if (t < 512) s[t] += v;
    __syncthreads();
  }
  if (t < 512) {
    int excl = (t > 0) ? s[t - 1] : 0;
    sofs[t] = excl;
    int node = (r << 9) + t;
    if (node < N_NODES) {
      off[node] = base + excl;
      dinv[node] = rsqrtf(1.f + (float)a);
    } else if (node == N_NODES) {
      off[node] = base + excl;   // boundary sentinel (last region only)
    }
  }
  __syncthreads();

  // counting sort into LDS (pairs slice is cache-hot)
  for (int i = t; i < cnt; i += 1024) {
    unsigned int p = pairs[base + i];
    int d = (int)((p >> 17) & 511);
    int lpos = sofs[d] + atomicAdd(&ncur[d], 1);
    if (lpos < REGION_CAP) cbuf[lpos] = (int)(p & 0x1FFFFu);
  }
  __syncthreads();
  for (int i = t; i < cnt; i += 1024) csr_src[base + i] = cbuf[i];
}

// ---------- MFMA GEMM: sxw_bf16 = bf16((x @ Wg) * dinv[row]) ----------
__global__ __launch_bounds__(256) void k_gemm(
    const float* __restrict__ x, const unsigned short* __restrict__ WgT,
    const float* __restrict__ dinv, unsigned short* __restrict__ sxw) {
  __shared__ unsigned short As[128][32];   // [m][k] bf16
  __shared__ unsigned short Bs[128][32];   // [n][k] bf16 (B^T)

  const int t = threadIdx.x;
  const int lane15 = t & 15;
  const int quad = (t & 63) >> 4;
  const int wave = t >> 6;
  const int wm = (wave & 1) * 64;
  const int wn = (wave >> 1) * 64;
  const int row0 = blockIdx.x * 128;

  f32x4 acc[4][4];
#pragma unroll
  for (int mi = 0; mi < 4; mi++)
#pragma unroll
    for (int ni = 0; ni < 4; ni++) acc[mi][ni] = (f32x4){0.f, 0.f, 0.f, 0.f};

  float4 ga[4];
  uint4 gb[2];
  auto load_tile = [&](int k0) {
#pragma unroll
    for (int i = 0; i < 4; i++) {
      int f = t + 256 * i;
      int r = f >> 3, c4 = f & 7;
      int gr = row0 + r;
      if (gr >= N_NODES) gr = N_NODES - 1;
      ga[i] = *(const float4*)&x[(size_t)gr * F_IN + k0 + c4 * 4];
    }
#pragma unroll
    for (int i = 0; i < 2; i++) {
      int f = t + 256 * i;
      int r = f >> 2, c = f & 3;
      gb[i] = *(const uint4*)&WgT[r * F_IN + k0 + c * 8];
    }
  };

  load_tile(0);
#pragma unroll 1
  for (int kt = 0; kt < 16; kt++) {
    __syncthreads();
#pragma unroll
    for (int i = 0; i < 4; i++) {
      int f = t + 256 * i;
      int r = f >> 3, c4 = f & 7;
      unsigned int u0 = f2bf2(ga[i].x, ga[i].y);
      unsigned int u1 = f2bf2(ga[i].z, ga[i].w);
      *(uint2*)&As[r][c4 * 4] = make_uint2(u0, u1);
    }
#pragma unroll
    for (int i = 0; i < 2; i++) {
      int f = t + 256 * i;
      int r = f >> 2, c = f & 3;
      *(uint4*)&Bs[r][c * 8] = gb[i];
    }
    __syncthreads();
    if (kt < 15) load_tile((kt + 1) * 32);

    short8 afr[4], bfr[4];
#pragma unroll
    for (int mi = 0; mi < 4; mi++)
      afr[mi] = *(const short8*)&As[wm + mi * 16 + lane15][quad * 8];
#pragma unroll
    for (int ni = 0; ni < 4; ni++)
      bfr[ni] = *(const short8*)&Bs[wn + ni * 16 + lane15][quad * 8];
#pragma unroll
    for (int mi = 0; mi < 4; mi++)
#pragma unroll
      for (int ni = 0; ni < 4; ni++)
        acc[mi][ni] = __builtin_amdgcn_mfma_f32_16x16x32_bf16(
            bfr[ni], afr[mi], acc[mi][ni], 0, 0, 0);
  }

#pragma unroll
  for (int mi = 0; mi < 4; mi++) {
    int gm = row0 + wm + mi * 16 + lane15;
    if (gm < N_NODES) {
      float s = dinv[gm];
#pragma unroll
      for (int ni = 0; ni < 4; ni++) {
        int gn = wn + ni * 16 + quad * 4;
        unsigned int u0 = f2bf2(acc[mi][ni][0] * s, acc[mi][ni][1] * s);
        unsigned int u1 = f2bf2(acc[mi][ni][2] * s, acc[mi][ni][3] * s);
        *(uint2*)&sxw[(size_t)gm * F_GNN + gn] = make_uint2(u0, u1);
      }
    }
  }
}

// ---------- fused aggregate + ReLU + mean/max pool: one block per graph ----------
// uint2 gather: 64-lane wave fetches 2 rows per load inst (h = lane>>5 picks edge)
// e1 clamped by region cursor (slabs are padded; off[n+1] overshoots at region tails)
__global__ __launch_bounds__(1024) void k_aggpool(
    const unsigned short* __restrict__ sxw, const int* __restrict__ off,
    const int* __restrict__ csr_src, const float* __restrict__ dinv,
    const float* __restrict__ bg, const int* __restrict__ batch,
    const int* __restrict__ cursor, float* __restrict__ gx) {
  __shared__ float4 ssum[16][32];
  __shared__ float4 smax[16][32];
  __shared__ int sse[2];
  const int g = blockIdx.x;
  const int t = threadIdx.x;
  const int wv = t >> 6;
  const int lane = t & 63;
  const int h = lane >> 5;      // which edge of the pair
  const int c = lane & 31;      // 8B feature chunk (4 bf16)

  if (t == 0) sse[0] = lower_bound_i(batch, N_NODES, g);
  if (t == 64) sse[1] = lower_bound_i(batch, N_NODES, g + 1);
  __syncthreads();
  const int start = sse[0], end = sse[1];

  const uint2* S2 = (const uint2*)sxw;  // 4 bf16 per uint2, row = 32 uint2
  float4 bb = ((const float4*)bg)[c];
  float ps0 = 0.f, ps1 = 0.f, ps2 = 0.f, ps3 = 0.f;
  float pm0 = 0.f, pm1 = 0.f, pm2 = 0.f, pm3 = 0.f;

  for (int node = start + wv; node < end; node += 16) {
    float sx0 = 0.f, sx1 = 0.f, sx2 = 0.f, sx3 = 0.f;
    int e = off[node];
    const int e1 = min(off[node + 1], cursor[node >> 9]);
    for (; e + 7 < e1; e += 8) {
      int s0 = csr_src[e + 0], s1 = csr_src[e + 1];
      int s2 = csr_src[e + 2], s3 = csr_src[e + 3];
      int s4 = csr_src[e + 4], s5 = csr_src[e + 5];
      int s6 = csr_src[e + 6], s7 = csr_src[e + 7];
      uint2 v0 = S2[(size_t)(h ? s1 : s0) * 32 + c];
      uint2 v1 = S2[(size_t)(h ? s3 : s2) * 32 + c];
      uint2 v2 = S2[(size_t)(h ? s5 : s4) * 32 + c];
      uint2 v3 = S2[(size_t)(h ? s7 : s6) * 32 + c];
      sx0 += bf_lo(v0.x) + bf_lo(v1.x) + bf_lo(v2.x) + bf_lo(v3.x);
      sx1 += bf_hi(v0.x) + bf_hi(v1.x) + bf_hi(v2.x) + bf_hi(v3.x);
      sx2 += bf_lo(v0.y) + bf_lo(v1.y) + bf_lo(v2.y) + bf_lo(v3.y);
      sx3 += bf_hi(v0.y) + bf_hi(v1.y) + bf_hi(v2.y) + bf_hi(v3.y);
    }
    for (; e + 1 < e1; e += 2) {
      int sa = csr_src[e], sb = csr_src[e + 1];
      uint2 v = S2[(size_t)(h ? sb : sa) * 32 + c];
      sx0 += bf_lo(v.x); sx1 += bf_hi(v.x);
      sx2 += bf_lo(v.y); sx3 += bf_hi(v.y);
    }
    if (e < e1 && h == 0) {
      uint2 v = S2[(size_t)csr_src[e] * 32 + c];
      sx0 += bf_lo(v.x); sx1 += bf_hi(v.x);
      sx2 += bf_lo(v.y); sx3 += bf_hi(v.y);
    }
    // combine the two half-wave edge partials
    sx0 += __shfl_xor(sx0, 32);
    sx1 += __shfl_xor(sx1, 32);
    sx2 += __shfl_xor(sx2, 32);
    sx3 += __shfl_xor(sx3, 32);
    // self-loop row
    uint2 sv = S2[(size_t)node * 32 + c];
    sx0 += bf_lo(sv.x); sx1 += bf_hi(sv.x);
    sx2 += bf_lo(sv.y); sx3 += bf_hi(sv.y);

    float di = dinv[node];
    float r0 = fmaxf(fmaf(sx0, di, bb.x), 0.f);
    float r1 = fmaxf(fmaf(sx1, di, bb.y), 0.f);
    float r2 = fmaxf(fmaf(sx2, di, bb.z), 0.f);
    float r3 = fmaxf(fmaf(sx3, di, bb.w), 0.f);
    ps0 += r0; ps1 += r1; ps2 += r2; ps3 += r3;
    pm0 = fmaxf(pm0, r0); pm1 = fmaxf(pm1, r1);
    pm2 = fmaxf(pm2, r2); pm3 = fmaxf(pm3, r3);
  }

  if (h == 0) {
    ssum[wv][c] = make_float4(ps0, ps1, ps2, ps3);
    smax[wv][c] = make_float4(pm0, pm1, pm2, pm3);
  }
  __syncthreads();
  if (t < 32) {
    float4 s = ssum[0][t];
    float4 m = smax[0][t];
#pragma unroll
    for (int hh = 1; hh < 16; hh++) {
      float4 a = ssum[hh][t], b2 = smax[hh][t];
      s.x += a.x; s.y += a.y; s.z += a.z; s.w += a.w;
      m.x = fmaxf(m.x, b2.x); m.y = fmaxf(m.y, b2.y);
      m.z = fmaxf(m.z, b2.z); m.w = fmaxf(m.w, b2.w);
    }
    float ic = 1.f / fmaxf((float)(end - start), 1.f);
    gx[g * 256 + 4 * t + 0] = s.x * ic;
    gx[g * 256 + 4 * t + 1] = s.y * ic;
    gx[g * 256 + 4 * t + 2] = s.z * ic;
    gx[g * 256 + 4 * t + 3] = s.w * ic;
    gx[g * 256 + 128 + 4 * t + 0] = m.x;
    gx[g * 256 + 128 + 4 * t + 1] = m.y;
    gx[g * 256 + 128 + 4 * t + 2] = m.z;
    gx[g * 256 + 128 + 4 * t + 3] = m.w;
  }
}

// ---------- encoder MLP + reparam + decoder MLP ----------
__global__ __launch_bounds__(64) void k_mlp(
    const float* __restrict__ gx, const float* __restrict__ eps,
    const float* __restrict__ We1, const float* __restrict__ be1,
    const float* __restrict__ We2, const float* __restrict__ be2,
    const float* __restrict__ We3, const float* __restrict__ be3,
    const float* __restrict__ Wd1, const float* __restrict__ bd1,
    const float* __restrict__ Wd2, const float* __restrict__ bd2,
    const float* __restrict__ Wd3, const float* __restrict__ bd3,
    float* __restrict__ out) {
  __shared__ float row[256];
  __shared__ float t1[64], t2[64], zz[64], d1[64], d2[64];
  int g = blockIdx.x;
  int j = threadIdx.x;

#pragma unroll
  for (int i = 0; i < 4; i++) row[j + 64 * i] = gx[g * 256 + j + 64 * i];
  __syncthreads();

  float s = be1[j];
#pragma unroll 4
  for (int k = 0; k < 256; k++) s = fmaf(row[k], We1[k * 64 + j], s);
  t1[j] = eluf(s);
  __syncthreads();

  s = be2[j];
#pragma unroll 4
  for (int k = 0; k < 64; k++) s = fmaf(t1[k], We2[k * 64 + j], s);
  t2[j] = tanhf(s);
  __syncthreads();

  float m = be3[j], lv = be3[64 + j];
#pragma unroll 4
  for (int k = 0; k < 64; k++) {
    float tv = t2[k];
    m = fmaf(tv, We3[k * 128 + j], m);
    lv = fmaf(tv, We3[k * 128 + 64 + j], lv);
  }
  float sd = 1e-6f + softplusf(lv);
  float z = fmaf(eps[g * 64 + j], sd, m);
  out[g * 64 + j] = m;                  // mu
  out[32768 + g * 64 + j] = sd;         // stddev
  zz[j] = z;
  __syncthreads();

  s = bd1[j];
#pragma unroll 4
  for (int k = 0; k < 64; k++) s = fmaf(zz[k], Wd1[k * 64 + j], s);
  d1[j] = tanhf(s);
  __syncthreads();

  s = bd2[j];
#pragma unroll 4
  for (int k = 0; k < 64; k++) s = fmaf(d1[k], Wd2[k * 64 + j], s);
  d2[j] = eluf(s);
  __syncthreads();

  float y0 = bd3[j], y1 = bd3[64 + j];
#pragma unroll 4
  for (int k = 0; k < 64; k++) {
    float dv = d2[k];
    y0 = fmaf(dv, Wd3[k * 128 + j], y0);
    y1 = fmaf(dv, Wd3[k * 128 + 64 + j], y1);
  }
  y0 = fminf(fmaxf(sigmoidf(y0), 1e-8f), 1.f - 1e-8f);
  y1 = fminf(fmaxf(sigmoidf(y1), 1e-8f), 1.f - 1e-8f);
  out[65536 + g * 128 + j] = y0;
  out[65536 + g * 128 + 64 + j] = y1;
}

extern "C" void kernel_launch(void* const* d_in, const int* in_sizes, int n_in,
                              void* d_out, int out_size, void* d_ws, size_t ws_size,
                              hipStream_t stream) {
  const float* x     = (const float*)d_in[0];
  const int*   ei    = (const int*)d_in[1];
  const int*   batch = (const int*)d_in[2];
  const float* eps   = (const float*)d_in[3];
  const float* Wg    = (const float*)d_in[4];
  const float* bg    = (const float*)d_in[5];
  const float* We1   = (const float*)d_in[6];
  const float* be1   = (const float*)d_in[7];
  const float* We2   = (const float*)d_in[8];
  const float* be2   = (const float*)d_in[9];
  const float* We3   = (const float*)d_in[10];
  const float* be3   = (const float*)d_in[11];
  const float* Wd1   = (const float*)d_in[12];
  const float* bd1   = (const float*)d_in[13];
  const float* Wd2   = (const float*)d_in[14];
  const float* bd2   = (const float*)d_in[15];
  const float* Wd3   = (const float*)d_in[16];
  const float* bd3   = (const float*)d_in[17];
  float* out = (float*)d_out;

  // workspace layout (4B element offsets); SLABS = 196*10240 = 2,007,040
  int*            cursor  = (int*)d_ws;                       // 256
  int*            off     = cursor + 256;                     // 100608 (100001 used)
  float*          dinv    = (float*)(off + 100608);           // 100352
  int*            csr_src = (int*)(dinv + 100352);            // 2007040 (padded slabs)
  unsigned int*   pairs   = (unsigned int*)(csr_src + 2007040); // 2007040 (padded slabs)
  unsigned short* WgT     = (unsigned short*)(pairs + 2007040); // 65536 bf16
  unsigned short* sxw     = WgT + 65536;                      // 12.8M bf16 (16B-aligned)
  float*          gx      = (float*)(sxw + 12800000);         // 131072

  k_init<<<256, 256, 0, stream>>>(Wg, WgT, cursor);
  k_bucket<<<(N_EDGES + 4095) / 4096, 512, 0, stream>>>(ei, cursor, pairs);
  k_region<<<N_REGIONS, 1024, 0, stream>>>(pairs, cursor, off, dinv, csr_src);
  k_gemm<<<(N_NODES + 127) / 128, 256, 0, stream>>>(x, WgT, dinv, sxw);
  k_aggpool<<<N_GRAPHS, 1024, 0, stream>>>(sxw, off, csr_src, dinv, bg, batch,
                                           cursor, gx);
  k_mlp<<<N_GRAPHS, 64, 0, stream>>>(gx, eps, We1, be1, We2, be2, We3, be3,
                                     Wd1, bd1, Wd2, bd2, Wd3, bd3, out);
}

// Round 7
// 498.701 us; speedup vs baseline: 3.6994x; 1.0221x over previous
//
#include <hip/hip_runtime.h>
#include <hip/hip_bf16.h>
#include <math.h>

#define N_NODES 100000
#define N_EDGES 1600000
#define F_IN 512
#define F_GNN 128
#define HID 64
#define Z_DIM 64
#define N_GRAPHS 512
#define N_REGIONS 196      // 512 nodes per region
#define REGION_CAP 10240   // slab size; mean 8163, sd ~90 -> +22 sigma

typedef __attribute__((ext_vector_type(8))) short short8;
typedef __attribute__((ext_vector_type(4))) float f32x4;

// ---------- small device helpers ----------
__device__ __forceinline__ float eluf(float v) { return v > 0.f ? v : expm1f(v); }
__device__ __forceinline__ float softplusf(float v) {
  return fmaxf(v, 0.f) + log1pf(expf(-fabsf(v)));
}
__device__ __forceinline__ float sigmoidf(float v) { return 1.f / (1.f + expf(-v)); }

__device__ __forceinline__ unsigned short f2bf(float f) {
  unsigned int u = __float_as_uint(f);
  u = (u + 0x7fffu + ((u >> 16) & 1u)) >> 16;
  return (unsigned short)u;
}
// packed f32x2 -> bf16x2 (low = a, high = b)
__device__ __forceinline__ unsigned int f2bf2(float a, float b) {
  __hip_bfloat162 h = __float22bfloat162_rn(make_float2(a, b));
  unsigned int u;
  __builtin_memcpy(&u, &h, 4);
  return u;
}
__device__ __forceinline__ float bf_lo(unsigned int u) { return __uint_as_float(u << 16); }
__device__ __forceinline__ float bf_hi(unsigned int u) { return __uint_as_float(u & 0xffff0000u); }

__device__ __forceinline__ int lower_bound_i(const int* __restrict__ a, int n, int v) {
  int lo = 0, hi = n;
  while (lo < hi) {
    int mid = (lo + hi) >> 1;
    if (a[mid] < v) lo = mid + 1; else hi = mid;
  }
  return lo;
}

// ---------- init: WgT transpose + seed region cursors at slab bases ----------
__global__ __launch_bounds__(256) void k_init(
    const float* __restrict__ Wg, unsigned short* __restrict__ WgT,
    int* __restrict__ cursor) {
  int i = blockIdx.x * 256 + threadIdx.x;   // 65536 total
  int n = i >> 9, k = i & 511;
  WgT[i] = f2bf(Wg[k * F_GNN + n]);
  if (i < 256) cursor[i] = i * REGION_CAP;
}

// ---------- pass 1: bucket edges into 196 fixed-capacity slabs, packed 4B ----------
__global__ __launch_bounds__(512) void k_bucket(
    const int* __restrict__ ei, int* __restrict__ cursor_r,
    unsigned int* __restrict__ pairs) {
  __shared__ int lhist[256];
  __shared__ int lofs[256];
  __shared__ int lcur[256];
  __shared__ int gbase[256];
  __shared__ int sc[256];
  __shared__ unsigned int lpairs[4096];   // 16 KB

  const int b = blockIdx.x, t = threadIdx.x;
  const int e0 = b * 4096;

  if (t < 256) { lhist[t] = 0; lcur[t] = 0; }
  __syncthreads();

  int srcv[8], dstv[8];
#pragma unroll
  for (int jj = 0; jj < 2; jj++) {
    int e = e0 + jj * 2048 + 4 * t;
    if (e < N_EDGES) {
      int4 s4 = *(const int4*)&ei[e];
      int4 d4 = *(const int4*)&ei[N_EDGES + e];
      srcv[4 * jj + 0] = s4.x; dstv[4 * jj + 0] = d4.x;
      srcv[4 * jj + 1] = s4.y; dstv[4 * jj + 1] = d4.y;
      srcv[4 * jj + 2] = s4.z; dstv[4 * jj + 2] = d4.z;
      srcv[4 * jj + 3] = s4.w; dstv[4 * jj + 3] = d4.w;
      atomicAdd(&lhist[d4.x >> 9], 1);
      atomicAdd(&lhist[d4.y >> 9], 1);
      atomicAdd(&lhist[d4.z >> 9], 1);
      atomicAdd(&lhist[d4.w >> 9], 1);
    } else {
      dstv[4 * jj + 0] = dstv[4 * jj + 1] = dstv[4 * jj + 2] = dstv[4 * jj + 3] = -1;
    }
  }
  __syncthreads();

  // exclusive scan of lhist -> lofs (first 256 threads)
  if (t < 256) sc[t] = lhist[t];
  __syncthreads();
#pragma unroll
  for (int d = 1; d < 256; d <<= 1) {
    int v = (t < 256 && t >= d) ? sc[t - d] : 0;
    __syncthreads();
    if (t < 256) sc[t] += v;
    __syncthreads();
  }
  if (t < 256) lofs[t] = (t > 0) ? sc[t - 1] : 0;
  if (t < N_REGIONS && lhist[t] > 0) gbase[t] = atomicAdd(&cursor_r[t], lhist[t]);
  __syncthreads();

  // local scatter into LDS, region-contiguous, packed (src 17b | dstl 9b << 17)
#pragma unroll
  for (int j = 0; j < 8; j++) {
    if (dstv[j] >= 0) {
      int r = dstv[j] >> 9;
      int pos = lofs[r] + atomicAdd(&lcur[r], 1);
      lpairs[pos] = (unsigned)srcv[j] | ((unsigned)(dstv[j] & 511) << 17);
    }
  }
  __syncthreads();

  // flush: wave w copies runs of regions w, w+8, ... (no binary search)
  const int w = t >> 6, lane = t & 63;
  for (int r = w; r < N_REGIONS; r += 8) {
    int n = lhist[r];
    if (n > 0) {
      int o = lofs[r];
      int gb = gbase[r];
      for (int i = lane; i < n; i += 64)
        pairs[gb + i] = lpairs[o + i];
    }
  }
}

// ---------- pass 2: per-region hist + scan -> off/dinv, counting sort -> csr_src ----------
__global__ __launch_bounds__(1024) void k_region(
    const unsigned int* __restrict__ pairs, const int* __restrict__ cursor,
    int* __restrict__ off, float* __restrict__ dinv, int* __restrict__ csr_src) {
  __shared__ int nh[512];
  __shared__ int sofs[512];
  __shared__ int s[512];
  __shared__ int ncur[512];
  __shared__ int cbuf[REGION_CAP];   // 40 KB

  const int r = blockIdx.x, t = threadIdx.x;
  const int base = r * REGION_CAP;
  const int cnt = min(cursor[r] - base, REGION_CAP);

  if (t < 512) { nh[t] = 0; ncur[t] = 0; }
  __syncthreads();

  // stage slab into registers (statically unrolled; <= 10 per thread)
  unsigned pk[10];
#pragma unroll
  for (int j = 0; j < 10; j++) {
    int i = t + j * 1024;
    pk[j] = (i < cnt) ? pairs[base + i] : 0u;
  }
#pragma unroll
  for (int j = 0; j < 10; j++) {
    int i = t + j * 1024;
    if (i < cnt) atomicAdd(&nh[(pk[j] >> 17) & 511], 1);
  }
  __syncthreads();

  // inclusive scan of 512 counts (first 512 threads)
  int a = (t < 512) ? nh[t] : 0;
  if (t < 512) s[t] = a;
  __syncthreads();
#pragma unroll
  for (int d = 1; d < 512; d <<= 1) {
    int v = (t < 512 && t >= d) ? s[t - d] : 0;
    __syncthreads();
    if (t < 512) s[t] += v;
    __syncthreads();
  }
  if (t < 512) {
    int excl = (t > 0) ? s[t - 1] : 0;
    sofs[t] = excl;
    int node = (r << 9) + t;
    if (node < N_NODES) {
      off[node] = base + excl;
      dinv[node] = rsqrtf(1.f + (float)a);
    } else if (node == N_NODES) {
      off[node] = base + excl;   // boundary sentinel (last region only)
    }
  }
  __syncthreads();

  // counting sort from registers into LDS
#pragma unroll
  for (int j = 0; j < 10; j++) {
    int i = t + j * 1024;
    if (i < cnt) {
      unsigned int p = pk[j];
      int d = (int)((p >> 17) & 511);
      int lpos = sofs[d] + atomicAdd(&ncur[d], 1);
      if (lpos < REGION_CAP) cbuf[lpos] = (int)(p & 0x1FFFFu);
    }
  }
  __syncthreads();
  for (int i = t; i < cnt; i += 1024) csr_src[base + i] = cbuf[i];
}

// ---------- MFMA GEMM: sxw_bf16 = bf16((x @ Wg) * dinv[row]) ----------
__global__ __launch_bounds__(256) void k_gemm(
    const float* __restrict__ x, const unsigned short* __restrict__ WgT,
    const float* __restrict__ dinv, unsigned short* __restrict__ sxw) {
  __shared__ unsigned short As[128][32];   // [m][k] bf16
  __shared__ unsigned short Bs[128][32];   // [n][k] bf16 (B^T)

  const int t = threadIdx.x;
  const int lane15 = t & 15;
  const int quad = (t & 63) >> 4;
  const int wave = t >> 6;
  const int wm = (wave & 1) * 64;
  const int wn = (wave >> 1) * 64;
  const int row0 = blockIdx.x * 128;

  f32x4 acc[4][4];
#pragma unroll
  for (int mi = 0; mi < 4; mi++)
#pragma unroll
    for (int ni = 0; ni < 4; ni++) acc[mi][ni] = (f32x4){0.f, 0.f, 0.f, 0.f};

  float4 ga[4];
  uint4 gb[2];
  auto load_tile = [&](int k0) {
#pragma unroll
    for (int i = 0; i < 4; i++) {
      int f = t + 256 * i;
      int r = f >> 3, c4 = f & 7;
      int gr = row0 + r;
      if (gr >= N_NODES) gr = N_NODES - 1;
      ga[i] = *(const float4*)&x[(size_t)gr * F_IN + k0 + c4 * 4];
    }
#pragma unroll
    for (int i = 0; i < 2; i++) {
      int f = t + 256 * i;
      int r = f >> 2, c = f & 3;
      gb[i] = *(const uint4*)&WgT[r * F_IN + k0 + c * 8];
    }
  };

  load_tile(0);
#pragma unroll 1
  for (int kt = 0; kt < 16; kt++) {
    __syncthreads();
#pragma unroll
    for (int i = 0; i < 4; i++) {
      int f = t + 256 * i;
      int r = f >> 3, c4 = f & 7;
      unsigned int u0 = f2bf2(ga[i].x, ga[i].y);
      unsigned int u1 = f2bf2(ga[i].z, ga[i].w);
      *(uint2*)&As[r][c4 * 4] = make_uint2(u0, u1);
    }
#pragma unroll
    for (int i = 0; i < 2; i++) {
      int f = t + 256 * i;
      int r = f >> 2, c = f & 3;
      *(uint4*)&Bs[r][c * 8] = gb[i];
    }
    __syncthreads();
    if (kt < 15) load_tile((kt + 1) * 32);

    short8 afr[4], bfr[4];
#pragma unroll
    for (int mi = 0; mi < 4; mi++)
      afr[mi] = *(const short8*)&As[wm + mi * 16 + lane15][quad * 8];
#pragma unroll
    for (int ni = 0; ni < 4; ni++)
      bfr[ni] = *(const short8*)&Bs[wn + ni * 16 + lane15][quad * 8];
#pragma unroll
    for (int mi = 0; mi < 4; mi++)
#pragma unroll
      for (int ni = 0; ni < 4; ni++)
        acc[mi][ni] = __builtin_amdgcn_mfma_f32_16x16x32_bf16(
            bfr[ni], afr[mi], acc[mi][ni], 0, 0, 0);
  }

#pragma unroll
  for (int mi = 0; mi < 4; mi++) {
    int gm = row0 + wm + mi * 16 + lane15;
    if (gm < N_NODES) {
      float s = dinv[gm];
#pragma unroll
      for (int ni = 0; ni < 4; ni++) {
        int gn = wn + ni * 16 + quad * 4;
        unsigned int u0 = f2bf2(acc[mi][ni][0] * s, acc[mi][ni][1] * s);
        unsigned int u1 = f2bf2(acc[mi][ni][2] * s, acc[mi][ni][3] * s);
        *(uint2*)&sxw[(size_t)gm * F_GNN + gn] = make_uint2(u0, u1);
      }
    }
  }
}

// ---------- fused aggregate + ReLU + mean/max pool: one block per graph ----------
// uint4 gather: 64 lanes = 4 edges x 16B chunks -> 1 VMEM inst per 4 edges.
// node made wave-uniform via readfirstlane so off/csr/dinv use the scalar path.
__global__ __launch_bounds__(1024) void k_aggpool(
    const unsigned short* __restrict__ sxw, const int* __restrict__ off,
    const int* __restrict__ csr_src, const float* __restrict__ dinv,
    const float* __restrict__ bg, const int* __restrict__ batch,
    const int* __restrict__ cursor, float* __restrict__ gx) {
  __shared__ float ssum[16][16][8];   // 16 KB
  __shared__ float smax[16][16][8];   // 16 KB
  __shared__ int sse[2];
  const int g = blockIdx.x;
  const int t = threadIdx.x;
  const int wv = t >> 6;
  const int lane = t & 63;
  const int h = lane >> 4;      // which edge of the quad (0..3)
  const int c = lane & 15;      // 16B feature chunk (8 bf16)

  if (t == 0) sse[0] = lower_bound_i(batch, N_NODES, g);
  if (t == 64) sse[1] = lower_bound_i(batch, N_NODES, g + 1);
  __syncthreads();
  const int start = sse[0], end = sse[1];

  const uint4* S4 = (const uint4*)sxw;  // 8 bf16 per uint4; row = 16 uint4
  float4 ba = ((const float4*)bg)[2 * c];
  float4 bb = ((const float4*)bg)[2 * c + 1];
  float ps0 = 0.f, ps1 = 0.f, ps2 = 0.f, ps3 = 0.f;
  float ps4 = 0.f, ps5 = 0.f, ps6 = 0.f, ps7 = 0.f;
  float pm0 = 0.f, pm1 = 0.f, pm2 = 0.f, pm3 = 0.f;
  float pm4 = 0.f, pm5 = 0.f, pm6 = 0.f, pm7 = 0.f;

  for (int nd = start + wv; nd < end; nd += 16) {
    const int node = __builtin_amdgcn_readfirstlane(nd);
    float sx0 = 0.f, sx1 = 0.f, sx2 = 0.f, sx3 = 0.f;
    float sx4 = 0.f, sx5 = 0.f, sx6 = 0.f, sx7 = 0.f;
    int e = off[node];
    const int e1 = min(off[node + 1], cursor[node >> 9]);

#define ACC8(v)                                         \
    sx0 += bf_lo((v).x); sx1 += bf_hi((v).x);           \
    sx2 += bf_lo((v).y); sx3 += bf_hi((v).y);           \
    sx4 += bf_lo((v).z); sx5 += bf_hi((v).z);           \
    sx6 += bf_lo((v).w); sx7 += bf_hi((v).w);

    for (; e + 7 < e1; e += 8) {
      int s0 = csr_src[e + 0], s1 = csr_src[e + 1];
      int s2 = csr_src[e + 2], s3 = csr_src[e + 3];
      int s4 = csr_src[e + 4], s5 = csr_src[e + 5];
      int s6 = csr_src[e + 6], s7 = csr_src[e + 7];
      int srcA = h < 2 ? (h == 0 ? s0 : s1) : (h == 2 ? s2 : s3);
      int srcB = h < 2 ? (h == 0 ? s4 : s5) : (h == 2 ? s6 : s7);
      uint4 va = S4[(size_t)srcA * 16 + c];
      uint4 vb = S4[(size_t)srcB * 16 + c];
      ACC8(va);
      ACC8(vb);
    }
    for (; e + 3 < e1; e += 4) {
      int s0 = csr_src[e + 0], s1 = csr_src[e + 1];
      int s2 = csr_src[e + 2], s3 = csr_src[e + 3];
      int srcA = h < 2 ? (h == 0 ? s0 : s1) : (h == 2 ? s2 : s3);
      uint4 va = S4[(size_t)srcA * 16 + c];
      ACC8(va);
    }
    if (e < e1) {
      int idx = min(e + h, e1 - 1);
      int srcA = csr_src[idx];
      uint4 va = S4[(size_t)srcA * 16 + c];
      if (e + h < e1) { ACC8(va); }
    }
#undef ACC8

    // combine the 4 h-group partials (bits 4 and 5 of lane)
    sx0 += __shfl_xor(sx0, 16); sx0 += __shfl_xor(sx0, 32);
    sx1 += __shfl_xor(sx1, 16); sx1 += __shfl_xor(sx1, 32);
    sx2 += __shfl_xor(sx2, 16); sx2 += __shfl_xor(sx2, 32);
    sx3 += __shfl_xor(sx3, 16); sx3 += __shfl_xor(sx3, 32);
    sx4 += __shfl_xor(sx4, 16); sx4 += __shfl_xor(sx4, 32);
    sx5 += __shfl_xor(sx5, 16); sx5 += __shfl_xor(sx5, 32);
    sx6 += __shfl_xor(sx6, 16); sx6 += __shfl_xor(sx6, 32);
    sx7 += __shfl_xor(sx7, 16); sx7 += __shfl_xor(sx7, 32);

    // self-loop row (h-groups load same chunk; redundant but uniform)
    uint4 sv = S4[(size_t)node * 16 + c];
    sx0 += bf_lo(sv.x); sx1 += bf_hi(sv.x);
    sx2 += bf_lo(sv.y); sx3 += bf_hi(sv.y);
    sx4 += bf_lo(sv.z); sx5 += bf_hi(sv.z);
    sx6 += bf_lo(sv.w); sx7 += bf_hi(sv.w);

    float di = dinv[node];
    float r0 = fmaxf(fmaf(sx0, di, ba.x), 0.f);
    float r1 = fmaxf(fmaf(sx1, di, ba.y), 0.f);
    float r2 = fmaxf(fmaf(sx2, di, ba.z), 0.f);
    float r3 = fmaxf(fmaf(sx3, di, ba.w), 0.f);
    float r4 = fmaxf(fmaf(sx4, di, bb.x), 0.f);
    float r5 = fmaxf(fmaf(sx5, di, bb.y), 0.f);
    float r6 = fmaxf(fmaf(sx6, di, bb.z), 0.f);
    float r7 = fmaxf(fmaf(sx7, di, bb.w), 0.f);
    ps0 += r0; ps1 += r1; ps2 += r2; ps3 += r3;
    ps4 += r4; ps5 += r5; ps6 += r6; ps7 += r7;
    pm0 = fmaxf(pm0, r0); pm1 = fmaxf(pm1, r1);
    pm2 = fmaxf(pm2, r2); pm3 = fmaxf(pm3, r3);
    pm4 = fmaxf(pm4, r4); pm5 = fmaxf(pm5, r5);
    pm6 = fmaxf(pm6, r6); pm7 = fmaxf(pm7, r7);
  }

  if (h == 0) {
    ssum[wv][c][0] = ps0; ssum[wv][c][1] = ps1;
    ssum[wv][c][2] = ps2; ssum[wv][c][3] = ps3;
    ssum[wv][c][4] = ps4; ssum[wv][c][5] = ps5;
    ssum[wv][c][6] = ps6; ssum[wv][c][7] = ps7;
    smax[wv][c][0] = pm0; smax[wv][c][1] = pm1;
    smax[wv][c][2] = pm2; smax[wv][c][3] = pm3;
    smax[wv][c][4] = pm4; smax[wv][c][5] = pm5;
    smax[wv][c][6] = pm6; smax[wv][c][7] = pm7;
  }
  __syncthreads();
  if (t < 128) {
    int cc = t >> 3, k = t & 7;
    float s = 0.f, m = 0.f;
#pragma unroll
    for (int w = 0; w < 16; w++) {
      s += ssum[w][cc][k];
      m = fmaxf(m, smax[w][cc][k]);
    }
    float ic = 1.f / fmaxf((float)(end - start), 1.f);
    gx[g * 256 + 8 * cc + k] = s * ic;
    gx[g * 256 + 128 + 8 * cc + k] = m;
  }
}

// ---------- encoder MLP + reparam + decoder MLP ----------
__global__ __launch_bounds__(64) void k_mlp(
    const float* __restrict__ gx, const float* __restrict__ eps,
    const float* __restrict__ We1, const float* __restrict__ be1,
    const float* __restrict__ We2, const float* __restrict__ be2,
    const float* __restrict__ We3, const float* __restrict__ be3,
    const float* __restrict__ Wd1, const float* __restrict__ bd1,
    const float* __restrict__ Wd2, const float* __restrict__ bd2,
    const float* __restrict__ Wd3, const float* __restrict__ bd3,
    float* __restrict__ out) {
  __shared__ float row[256];
  __shared__ float t1[64], t2[64], zz[64], d1[64], d2[64];
  int g = blockIdx.x;
  int j = threadIdx.x;

#pragma unroll
  for (int i = 0; i < 4; i++) row[j + 64 * i] = gx[g * 256 + j + 64 * i];
  __syncthreads();

  float s = be1[j];
#pragma unroll 4
  for (int k = 0; k < 256; k++) s = fmaf(row[k], We1[k * 64 + j], s);
  t1[j] = eluf(s);
  __syncthreads();

  s = be2[j];
#pragma unroll 4
  for (int k = 0; k < 64; k++) s = fmaf(t1[k], We2[k * 64 + j], s);
  t2[j] = tanhf(s);
  __syncthreads();

  float m = be3[j], lv = be3[64 + j];
#pragma unroll 4
  for (int k = 0; k < 64; k++) {
    float tv = t2[k];
    m = fmaf(tv, We3[k * 128 + j], m);
    lv = fmaf(tv, We3[k * 128 + 64 + j], lv);
  }
  float sd = 1e-6f + softplusf(lv);
  float z = fmaf(eps[g * 64 + j], sd, m);
  out[g * 64 + j] = m;                  // mu
  out[32768 + g * 64 + j] = sd;         // stddev
  zz[j] = z;
  __syncthreads();

  s = bd1[j];
#pragma unroll 4
  for (int k = 0; k < 64; k++) s = fmaf(zz[k], Wd1[k * 64 + j], s);
  d1[j] = tanhf(s);
  __syncthreads();

  s = bd2[j];
#pragma unroll 4
  for (int k = 0; k < 64; k++) s = fmaf(d1[k], Wd2[k * 64 + j], s);
  d2[j] = eluf(s);
  __syncthreads();

  float y0 = bd3[j], y1 = bd3[64 + j];
#pragma unroll 4
  for (int k = 0; k < 64; k++) {
    float dv = d2[k];
    y0 = fmaf(dv, Wd3[k * 128 + j], y0);
    y1 = fmaf(dv, Wd3[k * 128 + 64 + j], y1);
  }
  y0 = fminf(fmaxf(sigmoidf(y0), 1e-8f), 1.f - 1e-8f);
  y1 = fminf(fmaxf(sigmoidf(y1), 1e-8f), 1.f - 1e-8f);
  out[65536 + g * 128 + j] = y0;
  out[65536 + g * 128 + 64 + j] = y1;
}

extern "C" void kernel_launch(void* const* d_in, const int* in_sizes, int n_in,
                              void* d_out, int out_size, void* d_ws, size_t ws_size,
                              hipStream_t stream) {
  const float* x     = (const float*)d_in[0];
  const int*   ei    = (const int*)d_in[1];
  const int*   batch = (const int*)d_in[2];
  const float* eps   = (const float*)d_in[3];
  const float* Wg    = (const float*)d_in[4];
  const float* bg    = (const float*)d_in[5];
  const float* We1   = (const float*)d_in[6];
  const float* be1   = (const float*)d_in[7];
  const float* We2   = (const float*)d_in[8];
  const float* be2   = (const float*)d_in[9];
  const float* We3   = (const float*)d_in[10];
  const float* be3   = (const float*)d_in[11];
  const float* Wd1   = (const float*)d_in[12];
  const float* bd1   = (const float*)d_in[13];
  const float* Wd2   = (const float*)d_in[14];
  const float* bd2   = (const float*)d_in[15];
  const float* Wd3   = (const float*)d_in[16];
  const float* bd3   = (const float*)d_in[17];
  float* out = (float*)d_out;

  // workspace layout (4B element offsets); SLABS = 196*10240 = 2,007,040
  int*            cursor  = (int*)d_ws;                       // 256
  int*            off     = cursor + 256;                     // 100608 (100001 used)
  float*          dinv    = (float*)(off + 100608);           // 100352
  int*            csr_src = (int*)(dinv + 100352);            // 2007040 (padded slabs)
  unsigned int*   pairs   = (unsigned int*)(csr_src + 2007040); // 2007040 (padded slabs)
  unsigned short* WgT     = (unsigned short*)(pairs + 2007040); // 65536 bf16
  unsigned short* sxw     = WgT + 65536;                      // 12.8M bf16 (16B-aligned)
  float*          gx      = (float*)(sxw + 12800000);         // 131072

  k_init<<<256, 256, 0, stream>>>(Wg, WgT, cursor);
  k_bucket<<<(N_EDGES + 4095) / 4096, 512, 0, stream>>>(ei, cursor, pairs);
  k_region<<<N_REGIONS, 1024, 0, stream>>>(pairs, cursor, off, dinv, csr_src);
  k_gemm<<<(N_NODES + 127) / 128, 256, 0, stream>>>(x, WgT, dinv, sxw);
  k_aggpool<<<N_GRAPHS, 1024, 0, stream>>>(sxw, off, csr_src, dinv, bg, batch,
                                           cursor, gx);
  k_mlp<<<N_GRAPHS, 64, 0, stream>>>(gx, eps, We1, be1, We2, be2, We3, be3,
                                     Wd1, bd1, Wd2, bd2, Wd3, bd3, out);
}